// Round 1
// baseline (533.015 us; speedup 1.0000x reference)
//
#include <hip/hip_runtime.h>

// Problem: B=4, S=2048, D_MODEL=1024, H=16, DK=64.  M = B*S = 8192.
// Pipeline: cvt weights -> 6x swiglu GEMM (bf16) -> merge (silu*g2, split heads,
// V transposed) -> causal flash attention -> output GEMM (f32 + bias).

typedef __bf16 bf16;
typedef bf16 bf16x8 __attribute__((ext_vector_type(8)));
typedef float f32x4 __attribute__((ext_vector_type(4)));
typedef unsigned short u16;
typedef unsigned int u32;
typedef u16 u16x8 __attribute__((ext_vector_type(8)));

#define DEVI static __device__ __forceinline__

DEVI u16 f2b(float f) {                    // f32 -> bf16 bits, RNE
  union { float f; u32 u; } v; v.f = f;
  u32 r = v.u + 0x7FFFu + ((v.u >> 16) & 1u);
  return (u16)(r >> 16);
}
DEVI float b2f(u16 b) {
  union { u32 u; float f; } v; v.u = ((u32)b) << 16; return v.f;
}
DEVI f32x4 mfma16(bf16x8 a, bf16x8 b, f32x4 c) {
  return __builtin_amdgcn_mfma_f32_16x16x32_bf16(a, b, c, 0, 0, 0);
}

// ---------------------------------------------------------------------------
// Weight convert: 7 matrices of 1024x1024 f32 -> bf16, 8 elems/thread.
struct P7 { const float* p[7]; };

__global__ void cvt_w(P7 in, u16* __restrict__ out) {
  const int which = blockIdx.y;
  const float* src = in.p[which];
  u16* dst = out + (size_t)which * 1048576;
  const int i = blockIdx.x * 256 + threadIdx.x;     // grid.x = 512 -> 131072 thr
  const f32x4 a = ((const f32x4*)src)[i * 2];
  const f32x4 b = ((const f32x4*)src)[i * 2 + 1];
  u16x8 w;
#pragma unroll
  for (int j = 0; j < 4; ++j) { w[j] = f2b(a[j]); w[4 + j] = f2b(b[j]); }
  ((u16x8*)dst)[i] = w;
}

// ---------------------------------------------------------------------------
// GEMM: C[M,N] = A[M,K] * B[N,K]^T.  BM=128, BN=128, BK=64, 256 thr (4 waves,
// 2x2, 64x64 per wave).  Reg-staged LDS, XOR-swizzled (byte ^= (row&7)<<4) so
// frag ds_read_b128 is ~conflict-free.  A may be f32 (converted inline).
template<bool A_F32, bool OUT_BF16, bool BIAS>
__global__ __launch_bounds__(256, 2) void gemm_bt(
    const void* __restrict__ Ap, const u16* __restrict__ Bp,
    const float* __restrict__ bias, void* __restrict__ Cp,
    int M, int N, int K)
{
  __shared__ char smem[32768];
  char* As = smem;             // [128 rows][128 B] swizzled
  char* Bs = smem + 16384;     // [128 rows][128 B] swizzled
  const int t = threadIdx.x;
  const int lane = t & 63;
  const int lg = lane >> 4, lc = lane & 15;
  const int wid = t >> 6;
  const int wr = (wid >> 1) * 64, wc = (wid & 1) * 64;
  const int m0 = blockIdx.y * 128, n0 = blockIdx.x * 128;
  const int rs = t >> 3;             // staging row within 32-row pass block
  const int cb = (t & 7) << 4;       // staging byte col (0..112, step 16)

  const f32x4 fz = {0.f, 0.f, 0.f, 0.f};
  f32x4 acc[4][4];
#pragma unroll
  for (int i = 0; i < 4; ++i)
#pragma unroll
    for (int j = 0; j < 4; ++j) acc[i][j] = fz;

  const int nk = K >> 6;
  for (int kt = 0; kt < nk; ++kt) {
    const int k0 = kt << 6;
    f32x4 la[4][2];
    u16x8 lab[4];
    u16x8 lb[4];
#pragma unroll
    for (int p = 0; p < 4; ++p) {       // global -> regs (swizzled source col)
      const int row = p * 32 + rs;
      const int col = (cb ^ ((row & 7) << 4)) >> 1;   // bf16-element k offset
      if constexpr (A_F32) {
        const float* a = (const float*)Ap + (size_t)(m0 + row) * K + k0 + col;
        la[p][0] = *(const f32x4*)a;
        la[p][1] = *(const f32x4*)(a + 4);
      } else {
        lab[p] = *(const u16x8*)((const u16*)Ap + (size_t)(m0 + row) * K + k0 + col);
      }
      lb[p] = *(const u16x8*)(Bp + (size_t)(n0 + row) * K + k0 + col);
    }
    __syncthreads();                    // previous tile fully consumed
#pragma unroll
    for (int p = 0; p < 4; ++p) {       // regs -> LDS (linear dest)
      const int row = p * 32 + rs;
      if constexpr (A_F32) {
        u16x8 w;
#pragma unroll
        for (int j = 0; j < 4; ++j) { w[j] = f2b(la[p][0][j]); w[4 + j] = f2b(la[p][1][j]); }
        *(u16x8*)(As + row * 128 + cb) = w;
      } else {
        *(u16x8*)(As + row * 128 + cb) = lab[p];
      }
      *(u16x8*)(Bs + row * 128 + cb) = lb[p];
    }
    __syncthreads();
#pragma unroll
    for (int kh = 0; kh < 2; ++kh) {
      bf16x8 af[4], bfr[4];
#pragma unroll
      for (int mf = 0; mf < 4; ++mf) {
        const int r = wr + mf * 16 + lc;
        af[mf] = *(const bf16x8*)(As + r * 128 + ((kh * 64 + (lg << 4)) ^ ((r & 7) << 4)));
      }
#pragma unroll
      for (int nf = 0; nf < 4; ++nf) {
        const int r = wc + nf * 16 + lc;
        bfr[nf] = *(const bf16x8*)(Bs + r * 128 + ((kh * 64 + (lg << 4)) ^ ((r & 7) << 4)));
      }
#pragma unroll
      for (int mf = 0; mf < 4; ++mf)
#pragma unroll
        for (int nf = 0; nf < 4; ++nf)
          acc[mf][nf] = mfma16(af[mf], bfr[nf], acc[mf][nf]);
    }
  }
  // epilogue: C/D frag row = (lane>>4)*4 + j, col = lane&15
#pragma unroll
  for (int mf = 0; mf < 4; ++mf) {
#pragma unroll
    for (int nf = 0; nf < 4; ++nf) {
      const int r0 = m0 + wr + mf * 16 + (lg << 2);
      const int cc = n0 + wc + nf * 16 + lc;
      float bv = 0.f;
      if constexpr (BIAS) bv = bias[cc];
#pragma unroll
      for (int j = 0; j < 4; ++j) {
        const float vv = acc[mf][nf][j] + bv;
        if constexpr (OUT_BF16) ((u16*)Cp)[(size_t)(r0 + j) * N + cc] = f2b(vv);
        else                    ((float*)Cp)[(size_t)(r0 + j) * N + cc] = vv;
      }
    }
  }
}

// ---------------------------------------------------------------------------
// merge for Q/K: y = silu(g1+b1)*(g2+b2)*scale, write [B,H,S,64].
__global__ void merge_qk(const u16* __restrict__ g1, const u16* __restrict__ g2,
                         const float* __restrict__ b1, const float* __restrict__ b2,
                         u16* __restrict__ out, float scale)
{
  const int i = blockIdx.x * 256 + threadIdx.x;   // grid.x = 4096
  const int trow = i >> 7;
  const int n = (i & 127) << 3;
  const u16x8 v1 = ((const u16x8*)g1)[i];
  const u16x8 v2 = ((const u16x8*)g2)[i];
  u16x8 w;
#pragma unroll
  for (int j = 0; j < 8; ++j) {
    const float x = b2f(v1[j]) + b1[n + j];
    const float y = b2f(v2[j]) + b2[n + j];
    const float s = x / (1.f + __expf(-x));
    w[j] = f2b(s * y * scale);
  }
  const int b = trow >> 11, s = trow & 2047, h = n >> 6, d = n & 63;
  *(u16x8*)(out + (((size_t)(b * 16 + h) * 2048 + s) * 64 + d)) = w;
}

// merge for V: y = silu(g1+b1)*(g2+b2), write transposed [B,H,64,S] so the
// attention PV B-fragment reads are contiguous.  64x64 tile via LDS.
__global__ void merge_v(const u16* __restrict__ g1, const u16* __restrict__ g2,
                        const float* __restrict__ b1, const float* __restrict__ b2,
                        u16* __restrict__ out)
{
  __shared__ u16 tile[64][72];                 // +8 pad: transpose-read conflicts ~2-way
  const int t = threadIdx.x;
  const int bh = blockIdx.y, sblk = blockIdx.x;  // grid (32, 64)
  const int b = bh >> 4, h = bh & 15;
  {
    const int r = t >> 2, cq = t & 3;
    const int srow = sblk * 64 + r;
    const size_t base = ((size_t)(b * 2048 + srow)) * 1024 + h * 64 + cq * 16;
#pragma unroll
    for (int half = 0; half < 2; ++half) {
      const u16x8 v1 = *(const u16x8*)(g1 + base + half * 8);
      const u16x8 v2 = *(const u16x8*)(g2 + base + half * 8);
      u16x8 w;
#pragma unroll
      for (int j = 0; j < 8; ++j) {
        const int d = cq * 16 + half * 8 + j;
        const float x = b2f(v1[j]) + b1[h * 64 + d];
        const float y = b2f(v2[j]) + b2[h * 64 + d];
        const float s = x / (1.f + __expf(-x));
        w[j] = f2b(s * y);
      }
      *(u16x8*)(&tile[r][cq * 16 + half * 8]) = w;
    }
  }
  __syncthreads();
  {
    const int d = t >> 2, s0 = (t & 3) << 4;
    u16x8 w0, w1;
#pragma unroll
    for (int j = 0; j < 8; ++j) { w0[j] = tile[s0 + j][d]; w1[j] = tile[s0 + 8 + j][d]; }
    const size_t ob = ((size_t)(bh * 64 + d)) * 2048 + sblk * 64 + s0;
    *(u16x8*)(out + ob)     = w0;
    *(u16x8*)(out + ob + 8) = w1;
  }
}

// ---------------------------------------------------------------------------
// Causal flash attention.  Q pre-scaled by 1/8.  Q,K: [BH, S, 64].
// Vt: [BH, 64, S].  O: [B, S, H*64] bf16.  Block = 4 waves, 128 q-rows
// (32/wave).  K-tile = 64.  K/V staged in XOR-swizzled LDS; P goes through a
// per-wave swizzled LDS buffer to convert C-frag -> A-frag layout.
__global__ __launch_bounds__(256, 2) void attn_fwd(
    const u16* __restrict__ Q, const u16* __restrict__ Kk,
    const u16* __restrict__ Vt, u16* __restrict__ O)
{
  __shared__ char smem[32768];
  char* Ks = smem;                       // [64 kpos][128B] swizzled
  char* Vs = smem + 8192;                // [64 d   ][128B] swizzled (holds V^T tile)
  char* Pw = smem + 16384 + (threadIdx.x >> 6) * 4096;  // per-wave [32 q][128B]
  const int t = threadIdx.x;
  const int lane = t & 63, wid = t >> 6;
  const int lg = lane >> 4, lc = lane & 15;
  const int bh = blockIdx.y;
  const int q0 = blockIdx.x * 128;
  const int qw = q0 + wid * 32;          // this wave's first q row
  const int rs = t >> 3, cb = (t & 7) << 4;

  bf16x8 qf[2][2];                       // Q A-frags, held in regs for all tiles
#pragma unroll
  for (int mf = 0; mf < 2; ++mf)
#pragma unroll
    for (int kh = 0; kh < 2; ++kh) {
      const int r = qw + mf * 16 + lc;
      qf[mf][kh] = *(const bf16x8*)(Q + ((size_t)bh * 2048 + r) * 64 + kh * 32 + lg * 8);
    }

  const f32x4 fz = {0.f, 0.f, 0.f, 0.f};
  f32x4 o[2][4];
  float mrow[2][4], lrow[2][4];
#pragma unroll
  for (int mf = 0; mf < 2; ++mf) {
#pragma unroll
    for (int dn = 0; dn < 4; ++dn) o[mf][dn] = fz;
#pragma unroll
    for (int j = 0; j < 4; ++j) { mrow[mf][j] = -1e30f; lrow[mf][j] = 0.f; }
  }

  const int nt = (q0 >> 6) + 2;          // causal: tiles covering k <= q0+127
  for (int kt = 0; kt < nt; ++kt) {
    const int kbase = kt << 6;
    u16x8 lk[2], lv[2];
#pragma unroll
    for (int p = 0; p < 2; ++p) {
      const int row = p * 32 + rs;
      const int col = (cb ^ ((row & 7) << 4)) >> 1;
      lk[p] = *(const u16x8*)(Kk + ((size_t)bh * 2048 + kbase + row) * 64 + col);
      lv[p] = *(const u16x8*)(Vt + ((size_t)bh * 64 + row) * 2048 + kbase + col);
    }
    __syncthreads();
#pragma unroll
    for (int p = 0; p < 2; ++p) {
      const int row = p * 32 + rs;
      *(u16x8*)(Ks + row * 128 + cb) = lk[p];
      *(u16x8*)(Vs + row * 128 + cb) = lv[p];
    }
    __syncthreads();
    if (kbase <= qw + 31) {              // wave has unmasked work in this tile
      // --- QK^T ---
      f32x4 sf[2][4];
#pragma unroll
      for (int mf = 0; mf < 2; ++mf)
#pragma unroll
        for (int nf = 0; nf < 4; ++nf) sf[mf][nf] = fz;
#pragma unroll
      for (int kh = 0; kh < 2; ++kh) {
        bf16x8 kb[4];
#pragma unroll
        for (int nf = 0; nf < 4; ++nf) {
          const int r = nf * 16 + lc;
          kb[nf] = *(const bf16x8*)(Ks + r * 128 + ((kh * 64 + (lg << 4)) ^ ((r & 7) << 4)));
        }
#pragma unroll
        for (int mf = 0; mf < 2; ++mf)
#pragma unroll
          for (int nf = 0; nf < 4; ++nf)
            sf[mf][nf] = mfma16(qf[mf][kh], kb[nf], sf[mf][nf]);
      }
      // --- causal mask (only on diagonal-overlap tiles) ---
      if (kbase + 63 > qw) {
#pragma unroll
        for (int mf = 0; mf < 2; ++mf)
#pragma unroll
          for (int nf = 0; nf < 4; ++nf)
#pragma unroll
            for (int j = 0; j < 4; ++j) {
              const int qr = qw + mf * 16 + (lg << 2) + j;
              const int kc = kbase + nf * 16 + lc;
              if (kc > qr) sf[mf][nf][j] = -1e30f;
            }
      }
      // --- online softmax (rows live in 16-lane groups; butterfly over cols) ---
#pragma unroll
      for (int mf = 0; mf < 2; ++mf) {
        float pm[4];
#pragma unroll
        for (int j = 0; j < 4; ++j)
          pm[j] = fmaxf(fmaxf(sf[mf][0][j], sf[mf][1][j]), fmaxf(sf[mf][2][j], sf[mf][3][j]));
#pragma unroll
        for (int dd = 1; dd <= 8; dd <<= 1)
#pragma unroll
          for (int j = 0; j < 4; ++j)
            pm[j] = fmaxf(pm[j], __shfl_xor(pm[j], dd, 64));
        float scj[4];
#pragma unroll
        for (int j = 0; j < 4; ++j) {
          const float mn = fmaxf(mrow[mf][j], pm[j]);
          scj[j] = __expf(mrow[mf][j] - mn);
          mrow[mf][j] = mn;
          lrow[mf][j] *= scj[j];
        }
#pragma unroll
        for (int dn = 0; dn < 4; ++dn)
#pragma unroll
          for (int j = 0; j < 4; ++j)
            o[mf][dn][j] *= scj[j];
        float rsum[4] = {0.f, 0.f, 0.f, 0.f};
#pragma unroll
        for (int nf = 0; nf < 4; ++nf)
#pragma unroll
          for (int j = 0; j < 4; ++j) {
            const float p = __expf(sf[mf][nf][j] - mrow[mf][j]);
            sf[mf][nf][j] = p;
            rsum[j] += p;
          }
#pragma unroll
        for (int dd = 1; dd <= 8; dd <<= 1)
#pragma unroll
          for (int j = 0; j < 4; ++j)
            rsum[j] += __shfl_xor(rsum[j], dd, 64);
#pragma unroll
        for (int j = 0; j < 4; ++j) lrow[mf][j] += rsum[j];
        // write P (C-frag layout) into swizzled per-wave LDS
#pragma unroll
        for (int nf = 0; nf < 4; ++nf)
#pragma unroll
          for (int j = 0; j < 4; ++j) {
            const int pr = mf * 16 + (lg << 2) + j;
            const int pcb = (nf * 16 + lc) << 1;
            *(u16*)(Pw + pr * 128 + (pcb ^ ((pr & 7) << 4))) = f2b(sf[mf][nf][j]);
          }
      }
      // --- PV: A = P (from LDS), B = V^T rows (contiguous k) ---
#pragma unroll
      for (int kh = 0; kh < 2; ++kh) {
        bf16x8 pa[2];
#pragma unroll
        for (int mf = 0; mf < 2; ++mf) {
          const int pr = mf * 16 + lc;
          pa[mf] = *(const bf16x8*)(Pw + pr * 128 + ((kh * 64 + (lg << 4)) ^ ((pr & 7) << 4)));
        }
#pragma unroll
        for (int dn = 0; dn < 4; ++dn) {
          const int vr = dn * 16 + lc;
          const bf16x8 vb = *(const bf16x8*)(Vs + vr * 128 + ((kh * 64 + (lg << 4)) ^ ((vr & 7) << 4)));
#pragma unroll
          for (int mf = 0; mf < 2; ++mf)
            o[mf][dn] = mfma16(pa[mf], vb, o[mf][dn]);
        }
      }
    }
  }
  // epilogue: O[b, s, h*64+d] = o / l
  const int b = bh >> 4, h = bh & 15;
#pragma unroll
  for (int mf = 0; mf < 2; ++mf)
#pragma unroll
    for (int dn = 0; dn < 4; ++dn)
#pragma unroll
      for (int j = 0; j < 4; ++j) {
        const int s = qw + mf * 16 + (lg << 2) + j;
        const int d = dn * 16 + lc;
        const float v = o[mf][dn][j] / lrow[mf][j];
        O[((size_t)(b * 2048 + s) * 16 + h) * 64 + d] = f2b(v);
      }
}

// ---------------------------------------------------------------------------
extern "C" void kernel_launch(void* const* d_in, const int* in_sizes, int n_in,
                              void* d_out, int out_size, void* d_ws, size_t ws_size,
                              hipStream_t stream)
{
  (void)in_sizes; (void)n_in; (void)out_size; (void)ws_size;
  const float* xq  = (const float*)d_in[0];
  const float* xk  = (const float*)d_in[1];
  const float* xv  = (const float*)d_in[2];
  // d_in[3] = causal mask (tril) -- hardcoded in attn_fwd
  const float* wq1 = (const float*)d_in[4];
  const float* bq1 = (const float*)d_in[5];
  const float* wq2 = (const float*)d_in[6];
  const float* bq2 = (const float*)d_in[7];
  const float* wk1 = (const float*)d_in[8];
  const float* bk1 = (const float*)d_in[9];
  const float* wk2 = (const float*)d_in[10];
  const float* bk2 = (const float*)d_in[11];
  const float* wv1 = (const float*)d_in[12];
  const float* bv1 = (const float*)d_in[13];
  const float* wv2 = (const float*)d_in[14];
  const float* bv2 = (const float*)d_in[15];
  const float* wo  = (const float*)d_in[16];
  const float* bo  = (const float*)d_in[17];

  char* ws = (char*)d_ws;
  const size_t WSZ = (size_t)2 * 1024 * 1024;       // bytes per bf16 weight matrix
  const size_t XSZ = (size_t)8192 * 1024 * 2;       // bytes per bf16 activation
  u16* WB = (u16*)ws;                               // 7 converted weights
  u16* G1 = (u16*)(ws + 7 * WSZ);
  u16* G2 = (u16*)(ws + 7 * WSZ + 1 * XSZ);
  u16* QB = (u16*)(ws + 7 * WSZ + 2 * XSZ);         // [BH, S, 64], pre-scaled 1/8
  u16* KB = (u16*)(ws + 7 * WSZ + 3 * XSZ);         // [BH, S, 64]
  u16* VT = (u16*)(ws + 7 * WSZ + 4 * XSZ);         // [BH, 64, S]
  u16* AO = (u16*)(ws + 7 * WSZ + 5 * XSZ);         // [8192, 1024] attn out

  P7 p7 = {{wq1, wq2, wk1, wk2, wv1, wv2, wo}};
  cvt_w<<<dim3(512, 7), 256, 0, stream>>>(p7, WB);

  const dim3 gg(8, 64);   // (N/128, M/128)
  // Q projection
  gemm_bt<true, true, false><<<gg, 256, 0, stream>>>(xq, WB + 0 * 1048576, nullptr, G1, 8192, 1024, 1024);
  gemm_bt<true, true, false><<<gg, 256, 0, stream>>>(xq, WB + 1 * 1048576, nullptr, G2, 8192, 1024, 1024);
  merge_qk<<<4096, 256, 0, stream>>>(G1, G2, bq1, bq2, QB, 0.125f);
  // K projection
  gemm_bt<true, true, false><<<gg, 256, 0, stream>>>(xk, WB + 2 * 1048576, nullptr, G1, 8192, 1024, 1024);
  gemm_bt<true, true, false><<<gg, 256, 0, stream>>>(xk, WB + 3 * 1048576, nullptr, G2, 8192, 1024, 1024);
  merge_qk<<<4096, 256, 0, stream>>>(G1, G2, bk1, bk2, KB, 1.0f);
  // V projection (transposed output)
  gemm_bt<true, true, false><<<gg, 256, 0, stream>>>(xv, WB + 4 * 1048576, nullptr, G1, 8192, 1024, 1024);
  gemm_bt<true, true, false><<<gg, 256, 0, stream>>>(xv, WB + 5 * 1048576, nullptr, G2, 8192, 1024, 1024);
  merge_v<<<dim3(32, 64), 256, 0, stream>>>(G1, G2, bv1, bv2, VT);
  // attention
  attn_fwd<<<dim3(16, 64), 256, 0, stream>>>(QB, KB, VT, AO);
  // output projection
  gemm_bt<false, false, true><<<gg, 256, 0, stream>>>(AO, WB + 6 * 1048576, bo, (float*)d_out, 8192, 1024, 1024);
}

// Round 2
// 449.787 us; speedup vs baseline: 1.1850x; 1.1850x over previous
//
#include <hip/hip_runtime.h>

// Problem: B=4, S=2048, D_MODEL=1024, H=16, DK=64.  M = B*S = 8192.
// Pipeline: cvt weights -> per projection {GEMM1 (raw), GEMM2+merge epilogue}
// -> causal flash attention (pair-balanced grid) -> output GEMM (f32 + bias).

typedef __bf16 bf16;
typedef bf16 bf16x8 __attribute__((ext_vector_type(8)));
typedef float f32x4 __attribute__((ext_vector_type(4)));
typedef unsigned short u16;
typedef unsigned int u32;
typedef u16 u16x8 __attribute__((ext_vector_type(8)));
typedef u16 u16x4 __attribute__((ext_vector_type(4)));

#define DEVI static __device__ __forceinline__

DEVI u16 f2b(float f) {                    // f32 -> bf16 bits, RNE
  union { float f; u32 u; } v; v.f = f;
  u32 r = v.u + 0x7FFFu + ((v.u >> 16) & 1u);
  return (u16)(r >> 16);
}
DEVI float b2f(u16 b) {
  union { u32 u; float f; } v; v.u = ((u32)b) << 16; return v.f;
}
DEVI f32x4 mfma16(bf16x8 a, bf16x8 b, f32x4 c) {
  return __builtin_amdgcn_mfma_f32_16x16x32_bf16(a, b, c, 0, 0, 0);
}

// ---------------------------------------------------------------------------
// Weight convert: 7 matrices of 1024x1024 f32 -> bf16, 8 elems/thread.
struct P7 { const float* p[7]; };

__global__ void cvt_w(P7 in, u16* __restrict__ out) {
  const int which = blockIdx.y;
  const float* src = in.p[which];
  u16* dst = out + (size_t)which * 1048576;
  const int i = blockIdx.x * 256 + threadIdx.x;     // grid.x = 512 -> 131072 thr
  const f32x4 a = ((const f32x4*)src)[i * 2];
  const f32x4 b = ((const f32x4*)src)[i * 2 + 1];
  u16x8 w;
#pragma unroll
  for (int j = 0; j < 4; ++j) { w[j] = f2b(a[j]); w[4 + j] = f2b(b[j]); }
  ((u16x8*)dst)[i] = w;
}

// ---------------------------------------------------------------------------
// GEMM: C[M,N] = A[M,K] * B[N,K]^T.  BM=128, BN=128, BK=64, 256 thr (4 waves,
// 2x2, 64x64 per wave).  Reg-staged LDS, XOR-swizzled (byte ^= (row&7)<<4).
template<bool A_F32, bool OUT_BF16, bool BIAS>
__global__ __launch_bounds__(256, 2) void gemm_bt(
    const void* __restrict__ Ap, const u16* __restrict__ Bp,
    const float* __restrict__ bias, void* __restrict__ Cp,
    int M, int N, int K)
{
  __shared__ char smem[32768];
  char* As = smem;             // [128 rows][128 B] swizzled
  char* Bs = smem + 16384;     // [128 rows][128 B] swizzled
  const int t = threadIdx.x;
  const int lane = t & 63;
  const int lg = lane >> 4, lc = lane & 15;
  const int wid = t >> 6;
  const int wr = (wid >> 1) * 64, wc = (wid & 1) * 64;
  const int m0 = blockIdx.y * 128, n0 = blockIdx.x * 128;
  const int rs = t >> 3;             // staging row within 32-row pass block
  const int cb = (t & 7) << 4;       // staging byte col (0..112, step 16)

  const f32x4 fz = {0.f, 0.f, 0.f, 0.f};
  f32x4 acc[4][4];
#pragma unroll
  for (int i = 0; i < 4; ++i)
#pragma unroll
    for (int j = 0; j < 4; ++j) acc[i][j] = fz;

  const int nk = K >> 6;
  for (int kt = 0; kt < nk; ++kt) {
    const int k0 = kt << 6;
    f32x4 la[4][2];
    u16x8 lab[4];
    u16x8 lb[4];
#pragma unroll
    for (int p = 0; p < 4; ++p) {       // global -> regs (swizzled source col)
      const int row = p * 32 + rs;
      const int col = (cb ^ ((row & 7) << 4)) >> 1;   // bf16-element k offset
      if constexpr (A_F32) {
        const float* a = (const float*)Ap + (size_t)(m0 + row) * K + k0 + col;
        la[p][0] = *(const f32x4*)a;
        la[p][1] = *(const f32x4*)(a + 4);
      } else {
        lab[p] = *(const u16x8*)((const u16*)Ap + (size_t)(m0 + row) * K + k0 + col);
      }
      lb[p] = *(const u16x8*)(Bp + (size_t)(n0 + row) * K + k0 + col);
    }
    __syncthreads();                    // previous tile fully consumed
#pragma unroll
    for (int p = 0; p < 4; ++p) {       // regs -> LDS (linear dest)
      const int row = p * 32 + rs;
      if constexpr (A_F32) {
        u16x8 w;
#pragma unroll
        for (int j = 0; j < 4; ++j) { w[j] = f2b(la[p][0][j]); w[4 + j] = f2b(la[p][1][j]); }
        *(u16x8*)(As + row * 128 + cb) = w;
      } else {
        *(u16x8*)(As + row * 128 + cb) = lab[p];
      }
      *(u16x8*)(Bs + row * 128 + cb) = lb[p];
    }
    __syncthreads();
#pragma unroll
    for (int kh = 0; kh < 2; ++kh) {
      bf16x8 af[4], bfr[4];
#pragma unroll
      for (int mf = 0; mf < 4; ++mf) {
        const int r = wr + mf * 16 + lc;
        af[mf] = *(const bf16x8*)(As + r * 128 + ((kh * 64 + (lg << 4)) ^ ((r & 7) << 4)));
      }
#pragma unroll
      for (int nf = 0; nf < 4; ++nf) {
        const int r = wc + nf * 16 + lc;
        bfr[nf] = *(const bf16x8*)(Bs + r * 128 + ((kh * 64 + (lg << 4)) ^ ((r & 7) << 4)));
      }
#pragma unroll
      for (int mf = 0; mf < 4; ++mf)
#pragma unroll
        for (int nf = 0; nf < 4; ++nf)
          acc[mf][nf] = mfma16(af[mf], bfr[nf], acc[mf][nf]);
    }
  }
  // epilogue: C/D frag row = (lane>>4)*4 + j, col = lane&15
#pragma unroll
  for (int mf = 0; mf < 4; ++mf) {
#pragma unroll
    for (int nf = 0; nf < 4; ++nf) {
      const int r0 = m0 + wr + mf * 16 + (lg << 2);
      const int cc = n0 + wc + nf * 16 + lc;
      float bv = 0.f;
      if constexpr (BIAS) bv = bias[cc];
#pragma unroll
      for (int j = 0; j < 4; ++j) {
        const float vv = acc[mf][nf][j] + bv;
        if constexpr (OUT_BF16) ((u16*)Cp)[(size_t)(r0 + j) * N + cc] = f2b(vv);
        else                    ((float*)Cp)[(size_t)(r0 + j) * N + cc] = vv;
      }
    }
  }
}

// ---------------------------------------------------------------------------
// GEMM2 + merge epilogue: C2 = A*W2^T; reads G1 (raw A*W1^T, bf16);
// out = silu(G1+b1) * (C2+b2) * scale.
// MODE 0: write [B,H,S,64] (Q/K, scale folded).  MODE 1: write V^T [B,H,64,S].
template<int MODE>
__global__ __launch_bounds__(256, 2) void gemm_merge(
    const float* __restrict__ Ap, const u16* __restrict__ Bp,
    const u16* __restrict__ G1, const float* __restrict__ b1,
    const float* __restrict__ b2, u16* __restrict__ out,
    float scale, int M, int N, int K)
{
  __shared__ char smem[32768];
  char* As = smem;
  char* Bs = smem + 16384;
  const int t = threadIdx.x;
  const int lane = t & 63;
  const int lg = lane >> 4, lc = lane & 15;
  const int wid = t >> 6;
  const int wr = (wid >> 1) * 64, wc = (wid & 1) * 64;
  const int m0 = blockIdx.y * 128, n0 = blockIdx.x * 128;
  const int rs = t >> 3, cb = (t & 7) << 4;

  const f32x4 fz = {0.f, 0.f, 0.f, 0.f};
  f32x4 acc[4][4];
#pragma unroll
  for (int i = 0; i < 4; ++i)
#pragma unroll
    for (int j = 0; j < 4; ++j) acc[i][j] = fz;

  const int nk = K >> 6;
  for (int kt = 0; kt < nk; ++kt) {
    const int k0 = kt << 6;
    f32x4 la[4][2];
    u16x8 lb[4];
#pragma unroll
    for (int p = 0; p < 4; ++p) {
      const int row = p * 32 + rs;
      const int col = (cb ^ ((row & 7) << 4)) >> 1;
      const float* a = Ap + (size_t)(m0 + row) * K + k0 + col;
      la[p][0] = *(const f32x4*)a;
      la[p][1] = *(const f32x4*)(a + 4);
      lb[p] = *(const u16x8*)(Bp + (size_t)(n0 + row) * K + k0 + col);
    }
    __syncthreads();
#pragma unroll
    for (int p = 0; p < 4; ++p) {
      const int row = p * 32 + rs;
      u16x8 w;
#pragma unroll
      for (int j = 0; j < 4; ++j) { w[j] = f2b(la[p][0][j]); w[4 + j] = f2b(la[p][1][j]); }
      *(u16x8*)(As + row * 128 + cb) = w;
      *(u16x8*)(Bs + row * 128 + cb) = lb[p];
    }
    __syncthreads();
#pragma unroll
    for (int kh = 0; kh < 2; ++kh) {
      bf16x8 af[4], bfr[4];
#pragma unroll
      for (int mf = 0; mf < 4; ++mf) {
        const int r = wr + mf * 16 + lc;
        af[mf] = *(const bf16x8*)(As + r * 128 + ((kh * 64 + (lg << 4)) ^ ((r & 7) << 4)));
      }
#pragma unroll
      for (int nf = 0; nf < 4; ++nf) {
        const int r = wc + nf * 16 + lc;
        bfr[nf] = *(const bf16x8*)(Bs + r * 128 + ((kh * 64 + (lg << 4)) ^ ((r & 7) << 4)));
      }
#pragma unroll
      for (int mf = 0; mf < 4; ++mf)
#pragma unroll
        for (int nf = 0; nf < 4; ++nf)
          acc[mf][nf] = mfma16(af[mf], bfr[nf], acc[mf][nf]);
    }
  }
  // merge epilogue
#pragma unroll
  for (int mf = 0; mf < 4; ++mf) {
#pragma unroll
    for (int nf = 0; nf < 4; ++nf) {
      const int r0 = m0 + wr + mf * 16 + (lg << 2);
      const int cc = n0 + wc + nf * 16 + lc;
      const float b1v = b1[cc], b2v = b2[cc];
      const int h = cc >> 6, d = cc & 63;
      if constexpr (MODE == 0) {
#pragma unroll
        for (int j = 0; j < 4; ++j) {
          const int r = r0 + j;
          const float x = b2f(G1[(size_t)r * N + cc]) + b1v;
          const float y = acc[mf][nf][j] + b2v;
          const float v = (x / (1.f + __expf(-x))) * y * scale;
          const int bb = r >> 11, s = r & 2047;
          out[((size_t)(bb * 16 + h) * 2048 + s) * 64 + d] = f2b(v);
        }
      } else {
        u16x4 w;
#pragma unroll
        for (int j = 0; j < 4; ++j) {
          const int r = r0 + j;
          const float x = b2f(G1[(size_t)r * N + cc]) + b1v;
          const float y = acc[mf][nf][j] + b2v;
          w[j] = f2b((x / (1.f + __expf(-x))) * y);
        }
        const int bb = r0 >> 11, s = r0 & 2047;   // r0 % 4 == 0, no b crossing
        *(u16x4*)(out + ((size_t)(bb * 16 + h) * 64 + d) * 2048 + s) = w;
      }
    }
  }
}

// ---------------------------------------------------------------------------
// Causal flash attention, pair-balanced.  Q pre-scaled by 0.125*log2e (exp2
// domain).  Q,K: [BH, S, 64].  Vt: [BH, 64, S].  O: [B, S, H*64] bf16.
// grid (8, 64): block x handles q-blocks {x, 15-x} -> 34 k-tiles/block,
// uniform.  4 waves, 128 q-rows (32/wave) per q-block.  K-tile = 64.
__global__ __launch_bounds__(256, 2) void attn_fwd(
    const u16* __restrict__ Q, const u16* __restrict__ Kk,
    const u16* __restrict__ Vt, u16* __restrict__ O)
{
  __shared__ char smem[32768];
  char* Ks = smem;                       // [64 kpos][128B] swizzled
  char* Vs = smem + 8192;                // [64 d   ][128B] swizzled (V^T tile)
  char* Pw = smem + 16384 + (threadIdx.x >> 6) * 4096;  // per-wave [32 q][128B]
  const int t = threadIdx.x;
  const int lane = t & 63, wid = t >> 6;
  const int lg = lane >> 4, lc = lane & 15;
  const int bh = blockIdx.y;
  const int rs = t >> 3, cb = (t & 7) << 4;
  const int b = bh >> 4, h = bh & 15;
  const f32x4 fz = {0.f, 0.f, 0.f, 0.f};

  for (int pass = 0; pass < 2; ++pass) {
    const int qblk = pass ? (15 - blockIdx.x) : blockIdx.x;
    const int q0 = qblk * 128;
    const int qw = q0 + wid * 32;        // this wave's first q row

    bf16x8 qf[2][2];                     // Q A-frags held in regs all tiles
#pragma unroll
    for (int mf = 0; mf < 2; ++mf)
#pragma unroll
      for (int kh = 0; kh < 2; ++kh) {
        const int r = qw + mf * 16 + lc;
        qf[mf][kh] = *(const bf16x8*)(Q + ((size_t)bh * 2048 + r) * 64 + kh * 32 + lg * 8);
      }

    f32x4 o[2][4];
    float mrow[2][4], lrow[2][4];
#pragma unroll
    for (int mf = 0; mf < 2; ++mf) {
#pragma unroll
      for (int dn = 0; dn < 4; ++dn) o[mf][dn] = fz;
#pragma unroll
      for (int j = 0; j < 4; ++j) { mrow[mf][j] = -1e30f; lrow[mf][j] = 0.f; }
    }

    const int nt = 2 * qblk + 2;         // causal tile count
    for (int kt = 0; kt < nt; ++kt) {
      const int kbase = kt << 6;
      u16x8 lk[2], lv[2];
#pragma unroll
      for (int p = 0; p < 2; ++p) {
        const int row = p * 32 + rs;
        const int col = (cb ^ ((row & 7) << 4)) >> 1;
        lk[p] = *(const u16x8*)(Kk + ((size_t)bh * 2048 + kbase + row) * 64 + col);
        lv[p] = *(const u16x8*)(Vt + ((size_t)bh * 64 + row) * 2048 + kbase + col);
      }
      __syncthreads();                   // prior tile fully consumed
#pragma unroll
      for (int p = 0; p < 2; ++p) {
        const int row = p * 32 + rs;
        *(u16x8*)(Ks + row * 128 + cb) = lk[p];
        *(u16x8*)(Vs + row * 128 + cb) = lv[p];
      }
      __syncthreads();
      if (kbase <= qw + 31) {            // wave has unmasked work here
        // --- QK^T ---
        f32x4 sf[2][4];
#pragma unroll
        for (int mf = 0; mf < 2; ++mf)
#pragma unroll
          for (int nf = 0; nf < 4; ++nf) sf[mf][nf] = fz;
#pragma unroll
        for (int kh = 0; kh < 2; ++kh) {
          bf16x8 kb[4];
#pragma unroll
          for (int nf = 0; nf < 4; ++nf) {
            const int r = nf * 16 + lc;
            kb[nf] = *(const bf16x8*)(Ks + r * 128 + ((kh * 64 + (lg << 4)) ^ ((r & 7) << 4)));
          }
#pragma unroll
          for (int mf = 0; mf < 2; ++mf)
#pragma unroll
            for (int nf = 0; nf < 4; ++nf)
              sf[mf][nf] = mfma16(qf[mf][kh], kb[nf], sf[mf][nf]);
        }
        // --- causal mask (diagonal-overlap tiles only) ---
        if (kbase + 63 > qw) {
#pragma unroll
          for (int mf = 0; mf < 2; ++mf)
#pragma unroll
            for (int nf = 0; nf < 4; ++nf)
#pragma unroll
              for (int j = 0; j < 4; ++j) {
                const int qr = qw + mf * 16 + (lg << 2) + j;
                const int kc = kbase + nf * 16 + lc;
                if (kc > qr) sf[mf][nf][j] = -1e30f;
              }
        }
        // --- online softmax, exp2 domain, defer-rescale ---
#pragma unroll
        for (int mf = 0; mf < 2; ++mf) {
          float pm[4];
#pragma unroll
          for (int j = 0; j < 4; ++j)
            pm[j] = fmaxf(fmaxf(sf[mf][0][j], sf[mf][1][j]), fmaxf(sf[mf][2][j], sf[mf][3][j]));
#pragma unroll
          for (int dd = 1; dd <= 8; dd <<= 1)
#pragma unroll
            for (int j = 0; j < 4; ++j)
              pm[j] = fmaxf(pm[j], __shfl_xor(pm[j], dd, 64));
          bool grow = false;
#pragma unroll
          for (int j = 0; j < 4; ++j) grow |= (pm[j] > mrow[mf][j]);
          if (__any(grow)) {             // rescale only when the max moved
            float scj[4];
#pragma unroll
            for (int j = 0; j < 4; ++j) {
              const float mn = fmaxf(mrow[mf][j], pm[j]);
              scj[j] = exp2f(mrow[mf][j] - mn);
              mrow[mf][j] = mn;
              lrow[mf][j] *= scj[j];
            }
#pragma unroll
            for (int dn = 0; dn < 4; ++dn)
#pragma unroll
              for (int j = 0; j < 4; ++j)
                o[mf][dn][j] *= scj[j];
          }
          float rsum[4] = {0.f, 0.f, 0.f, 0.f};
#pragma unroll
          for (int nf = 0; nf < 4; ++nf)
#pragma unroll
            for (int j = 0; j < 4; ++j) {
              const float p = exp2f(sf[mf][nf][j] - mrow[mf][j]);
              sf[mf][nf][j] = p;
              rsum[j] += p;
            }
#pragma unroll
          for (int dd = 1; dd <= 8; dd <<= 1)
#pragma unroll
            for (int j = 0; j < 4; ++j)
              rsum[j] += __shfl_xor(rsum[j], dd, 64);
#pragma unroll
          for (int j = 0; j < 4; ++j) lrow[mf][j] += rsum[j];
          // write P (C-frag layout) into swizzled per-wave LDS
#pragma unroll
          for (int nf = 0; nf < 4; ++nf)
#pragma unroll
            for (int j = 0; j < 4; ++j) {
              const int pr = mf * 16 + (lg << 2) + j;
              const int pcb = (nf * 16 + lc) << 1;
              *(u16*)(Pw + pr * 128 + (pcb ^ ((pr & 7) << 4))) = f2b(sf[mf][nf][j]);
            }
        }
        // --- PV: A = P (from LDS), B = V^T rows (contiguous k) ---
#pragma unroll
        for (int kh = 0; kh < 2; ++kh) {
          bf16x8 pa[2];
#pragma unroll
          for (int mf = 0; mf < 2; ++mf) {
            const int pr = mf * 16 + lc;
            pa[mf] = *(const bf16x8*)(Pw + pr * 128 + ((kh * 64 + (lg << 4)) ^ ((pr & 7) << 4)));
          }
#pragma unroll
          for (int dn = 0; dn < 4; ++dn) {
            const int vr = dn * 16 + lc;
            const bf16x8 vb = *(const bf16x8*)(Vs + vr * 128 + ((kh * 64 + (lg << 4)) ^ ((vr & 7) << 4)));
#pragma unroll
            for (int mf = 0; mf < 2; ++mf)
              o[mf][dn] = mfma16(pa[mf], vb, o[mf][dn]);
          }
        }
      }
    }
    // epilogue: O[b, s, h*64+d] = o / l
#pragma unroll
    for (int mf = 0; mf < 2; ++mf)
#pragma unroll
      for (int dn = 0; dn < 4; ++dn)
#pragma unroll
        for (int j = 0; j < 4; ++j) {
          const int s = qw + mf * 16 + (lg << 2) + j;
          const int d = dn * 16 + lc;
          const float v = o[mf][dn][j] / lrow[mf][j];
          O[((size_t)(b * 2048 + s) * 16 + h) * 64 + d] = f2b(v);
        }
  }
}

// ---------------------------------------------------------------------------
extern "C" void kernel_launch(void* const* d_in, const int* in_sizes, int n_in,
                              void* d_out, int out_size, void* d_ws, size_t ws_size,
                              hipStream_t stream)
{
  (void)in_sizes; (void)n_in; (void)out_size; (void)ws_size;
  const float* xq  = (const float*)d_in[0];
  const float* xk  = (const float*)d_in[1];
  const float* xv  = (const float*)d_in[2];
  // d_in[3] = causal mask (tril) -- hardcoded in attn_fwd
  const float* wq1 = (const float*)d_in[4];
  const float* bq1 = (const float*)d_in[5];
  const float* wq2 = (const float*)d_in[6];
  const float* bq2 = (const float*)d_in[7];
  const float* wk1 = (const float*)d_in[8];
  const float* bk1 = (const float*)d_in[9];
  const float* wk2 = (const float*)d_in[10];
  const float* bk2 = (const float*)d_in[11];
  const float* wv1 = (const float*)d_in[12];
  const float* bv1 = (const float*)d_in[13];
  const float* wv2 = (const float*)d_in[14];
  const float* bv2 = (const float*)d_in[15];
  const float* wo  = (const float*)d_in[16];
  const float* bo  = (const float*)d_in[17];

  char* ws = (char*)d_ws;
  const size_t WSZ = (size_t)2 * 1024 * 1024;       // bytes per bf16 weight matrix
  const size_t XSZ = (size_t)8192 * 1024 * 2;       // bytes per bf16 activation
  u16* WB = (u16*)ws;                               // 7 converted weights
  u16* G1 = (u16*)(ws + 7 * WSZ);                   // raw A*W1^T scratch
  u16* QB = (u16*)(ws + 7 * WSZ + 1 * XSZ);         // [BH, S, 64], exp2-prescaled
  u16* KB = (u16*)(ws + 7 * WSZ + 2 * XSZ);         // [BH, S, 64]
  u16* VT = (u16*)(ws + 7 * WSZ + 3 * XSZ);         // [BH, 64, S]
  u16* AO = (u16*)(ws + 7 * WSZ + 4 * XSZ);         // [8192, 1024] attn out

  P7 p7 = {{wq1, wq2, wk1, wk2, wv1, wv2, wo}};
  cvt_w<<<dim3(512, 7), 256, 0, stream>>>(p7, WB);

  const dim3 gg(8, 64);   // (N/128, M/128)
  const float QSCALE = 0.125f * 1.44269504088896f;  // 1/sqrt(dk) * log2(e)
  // Q projection
  gemm_bt<true, true, false><<<gg, 256, 0, stream>>>(xq, WB + 0 * 1048576, nullptr, G1, 8192, 1024, 1024);
  gemm_merge<0><<<gg, 256, 0, stream>>>(xq, WB + 1 * 1048576, G1, bq1, bq2, QB, QSCALE, 8192, 1024, 1024);
  // K projection
  gemm_bt<true, true, false><<<gg, 256, 0, stream>>>(xk, WB + 2 * 1048576, nullptr, G1, 8192, 1024, 1024);
  gemm_merge<0><<<gg, 256, 0, stream>>>(xk, WB + 3 * 1048576, G1, bk1, bk2, KB, 1.0f, 8192, 1024, 1024);
  // V projection (transposed output)
  gemm_bt<true, true, false><<<gg, 256, 0, stream>>>(xv, WB + 4 * 1048576, nullptr, G1, 8192, 1024, 1024);
  gemm_merge<1><<<gg, 256, 0, stream>>>(xv, WB + 5 * 1048576, G1, bv1, bv2, VT, 1.0f, 8192, 1024, 1024);
  // attention (pair-balanced grid)
  attn_fwd<<<dim3(8, 64), 256, 0, stream>>>(QB, KB, VT, AO);
  // output projection
  gemm_bt<false, false, true><<<gg, 256, 0, stream>>>(AO, WB + 6 * 1048576, bo, (float*)d_out, 8192, 1024, 1024);
}

// Round 3
// 352.624 us; speedup vs baseline: 1.5116x; 1.2755x over previous
//
#include <hip/hip_runtime.h>

// B=4, S=2048, D_MODEL=1024, H=16, DK=64.  M = B*S = 8192.
// Pipeline: cvt weights -> per projection {cvt act, GEMM1, GEMM2+merge}
// -> causal flash attention (pair-balanced, 2-phase pipelined) -> out GEMM.
// All GEMM/attn staging via global_load_lds (dwordx4), dbuf + 1 barrier/step.

typedef __bf16 bf16;
typedef bf16 bf16x8 __attribute__((ext_vector_type(8)));
typedef float f32x4 __attribute__((ext_vector_type(4)));
typedef unsigned short u16;
typedef unsigned int u32;
typedef u16 u16x8 __attribute__((ext_vector_type(8)));
typedef u16 u16x4 __attribute__((ext_vector_type(4)));

#define DEVI static __device__ __forceinline__

DEVI u16 f2b(float f) {                    // f32 -> bf16 bits, RNE
  union { float f; u32 u; } v; v.f = f;
  u32 r = v.u + 0x7FFFu + ((v.u >> 16) & 1u);
  return (u16)(r >> 16);
}
DEVI float b2f(u16 b) {
  union { u32 u; float f; } v; v.u = ((u32)b) << 16; return v.f;
}
DEVI f32x4 mfma16(bf16x8 a, bf16x8 b, f32x4 c) {
  return __builtin_amdgcn_mfma_f32_16x16x32_bf16(a, b, c, 0, 0, 0);
}
// async global -> LDS, 16B per lane.  LDS dest = wave-uniform base + lane*16.
DEVI void gload16(const void* g, void* l) {
  __builtin_amdgcn_global_load_lds(
      (const __attribute__((address_space(1))) void*)g,
      (__attribute__((address_space(3))) void*)l, 16, 0, 0);
}

// ---------------------------------------------------------------------------
// Weight convert: 7 matrices of 1024x1024 f32 -> bf16.
struct P7 { const float* p[7]; };

__global__ void cvt_w(P7 in, u16* __restrict__ out) {
  const int which = blockIdx.y;
  const float* src = in.p[which];
  u16* dst = out + (size_t)which * 1048576;
  const int i = blockIdx.x * 256 + threadIdx.x;     // grid.x = 512
  const f32x4 a = ((const f32x4*)src)[i * 2];
  const f32x4 b = ((const f32x4*)src)[i * 2 + 1];
  u16x8 w;
#pragma unroll
  for (int j = 0; j < 4; ++j) { w[j] = f2b(a[j]); w[4 + j] = f2b(b[j]); }
  ((u16x8*)dst)[i] = w;
}

// Activation convert: 8192x1024 f32 -> bf16 (one matrix per launch).
__global__ void cvt_x(const float* __restrict__ src, u16* __restrict__ dst) {
  const int i = blockIdx.x * 256 + threadIdx.x;     // grid.x = 4096
  const f32x4 a = ((const f32x4*)src)[i * 2];
  const f32x4 b = ((const f32x4*)src)[i * 2 + 1];
  u16x8 w;
#pragma unroll
  for (int j = 0; j < 4; ++j) { w[j] = f2b(a[j]); w[4 + j] = f2b(b[j]); }
  ((u16x8*)dst)[i] = w;
}

// ---------------------------------------------------------------------------
// GEMM: C[M,N] = A[M,K]*B[N,K]^T, bf16 in.  BM=BN=128, BK=64, 4 waves (2x2).
// global_load_lds staging, double-buffered, 1 barrier/K-step.
// Source col pre-swizzled, LDS linear, frag reads XOR-swizzled.
template<bool OUT_BF16, bool BIAS>
__global__ __launch_bounds__(256, 2) void gemm_bt(
    const u16* __restrict__ Ap, const u16* __restrict__ Bp,
    const float* __restrict__ bias, void* __restrict__ Cp,
    int N, int K)
{
  __shared__ char smem[65536];                 // 2 x (As 16K | Bs 16K)
  const int t = threadIdx.x;
  const int lane = t & 63;
  const int lg = lane >> 4, lc = lane & 15;
  const int wid = t >> 6;
  const int wr = (wid >> 1) * 64, wc = (wid & 1) * 64;
  const int m0 = blockIdx.y * 128, n0 = blockIdx.x * 128;
  const int srow = lane >> 3;                  // 0..7 within 8-row chunk
  const int scolb = (lane & 7) << 4;           // byte col 0..112

  const f32x4 fz = {0.f, 0.f, 0.f, 0.f};
  f32x4 acc[4][4];
#pragma unroll
  for (int i = 0; i < 4; ++i)
#pragma unroll
    for (int j = 0; j < 4; ++j) acc[i][j] = fz;

  const int nk = K >> 6;
  auto STAGE = [&](int buf, int kt) {
    const int k0 = kt << 6;
    char* As = smem + buf * 32768;
    char* Bs = As + 16384;
#pragma unroll
    for (int p = 0; p < 4; ++p) {
      const int rb = wid * 32 + p * 8;         // wave-uniform chunk base
      const int row = rb + srow;
      const int ce = (scolb ^ ((row & 7) << 4)) >> 1;   // element col
      gload16(Ap + (size_t)(m0 + row) * K + k0 + ce, As + rb * 128);
      gload16(Bp + (size_t)(n0 + row) * K + k0 + ce, Bs + rb * 128);
    }
  };

  STAGE(0, 0);
  __syncthreads();                             // drains stage 0
  for (int kt = 0; kt < nk; ++kt) {
    const int cur = kt & 1;
    if (kt + 1 < nk) STAGE(cur ^ 1, kt + 1);   // issue next tile early
    const char* As = smem + cur * 32768;
    const char* Bs = As + 16384;
#pragma unroll
    for (int kh = 0; kh < 2; ++kh) {
      bf16x8 af[4], bfr[4];
#pragma unroll
      for (int mf = 0; mf < 4; ++mf) {
        const int r = wr + mf * 16 + lc;
        af[mf] = *(const bf16x8*)(As + r * 128 + ((kh * 64 + (lg << 4)) ^ ((r & 7) << 4)));
      }
#pragma unroll
      for (int nf = 0; nf < 4; ++nf) {
        const int r = wc + nf * 16 + lc;
        bfr[nf] = *(const bf16x8*)(Bs + r * 128 + ((kh * 64 + (lg << 4)) ^ ((r & 7) << 4)));
      }
#pragma unroll
      for (int mf = 0; mf < 4; ++mf)
#pragma unroll
        for (int nf = 0; nf < 4; ++nf)
          acc[mf][nf] = mfma16(af[mf], bfr[nf], acc[mf][nf]);
    }
    __syncthreads();                           // next buffer ready; LDS reusable
  }
  // epilogue: C/D frag row = (lane>>4)*4 + j, col = lane&15
#pragma unroll
  for (int mf = 0; mf < 4; ++mf) {
#pragma unroll
    for (int nf = 0; nf < 4; ++nf) {
      const int r0 = m0 + wr + mf * 16 + (lg << 2);
      const int cc = n0 + wc + nf * 16 + lc;
      float bv = 0.f;
      if constexpr (BIAS) bv = bias[cc];
#pragma unroll
      for (int j = 0; j < 4; ++j) {
        const float vv = acc[mf][nf][j] + bv;
        if constexpr (OUT_BF16) ((u16*)Cp)[(size_t)(r0 + j) * N + cc] = f2b(vv);
        else                    ((float*)Cp)[(size_t)(r0 + j) * N + cc] = vv;
      }
    }
  }
}

// ---------------------------------------------------------------------------
// GEMM2 + merge: C2 = A*W2^T; out = silu(G1+b1)*(C2+b2)*scale.
// MODE 0: write [B,H,S,64] (Q/K).  MODE 1: write V^T [B,H,64,S].
template<int MODE>
__global__ __launch_bounds__(256, 2) void gemm_merge(
    const u16* __restrict__ Ap, const u16* __restrict__ Bp,
    const u16* __restrict__ G1, const float* __restrict__ b1,
    const float* __restrict__ b2, u16* __restrict__ out,
    float scale, int N, int K)
{
  __shared__ char smem[65536];
  const int t = threadIdx.x;
  const int lane = t & 63;
  const int lg = lane >> 4, lc = lane & 15;
  const int wid = t >> 6;
  const int wr = (wid >> 1) * 64, wc = (wid & 1) * 64;
  const int m0 = blockIdx.y * 128, n0 = blockIdx.x * 128;
  const int srow = lane >> 3;
  const int scolb = (lane & 7) << 4;

  const f32x4 fz = {0.f, 0.f, 0.f, 0.f};
  f32x4 acc[4][4];
#pragma unroll
  for (int i = 0; i < 4; ++i)
#pragma unroll
    for (int j = 0; j < 4; ++j) acc[i][j] = fz;

  const int nk = K >> 6;
  auto STAGE = [&](int buf, int kt) {
    const int k0 = kt << 6;
    char* As = smem + buf * 32768;
    char* Bs = As + 16384;
#pragma unroll
    for (int p = 0; p < 4; ++p) {
      const int rb = wid * 32 + p * 8;
      const int row = rb + srow;
      const int ce = (scolb ^ ((row & 7) << 4)) >> 1;
      gload16(Ap + (size_t)(m0 + row) * K + k0 + ce, As + rb * 128);
      gload16(Bp + (size_t)(n0 + row) * K + k0 + ce, Bs + rb * 128);
    }
  };

  STAGE(0, 0);
  __syncthreads();
  for (int kt = 0; kt < nk; ++kt) {
    const int cur = kt & 1;
    if (kt + 1 < nk) STAGE(cur ^ 1, kt + 1);
    const char* As = smem + cur * 32768;
    const char* Bs = As + 16384;
#pragma unroll
    for (int kh = 0; kh < 2; ++kh) {
      bf16x8 af[4], bfr[4];
#pragma unroll
      for (int mf = 0; mf < 4; ++mf) {
        const int r = wr + mf * 16 + lc;
        af[mf] = *(const bf16x8*)(As + r * 128 + ((kh * 64 + (lg << 4)) ^ ((r & 7) << 4)));
      }
#pragma unroll
      for (int nf = 0; nf < 4; ++nf) {
        const int r = wc + nf * 16 + lc;
        bfr[nf] = *(const bf16x8*)(Bs + r * 128 + ((kh * 64 + (lg << 4)) ^ ((r & 7) << 4)));
      }
#pragma unroll
      for (int mf = 0; mf < 4; ++mf)
#pragma unroll
        for (int nf = 0; nf < 4; ++nf)
          acc[mf][nf] = mfma16(af[mf], bfr[nf], acc[mf][nf]);
    }
    __syncthreads();
  }
  // merge epilogue
#pragma unroll
  for (int mf = 0; mf < 4; ++mf) {
#pragma unroll
    for (int nf = 0; nf < 4; ++nf) {
      const int r0 = m0 + wr + mf * 16 + (lg << 2);
      const int cc = n0 + wc + nf * 16 + lc;
      const float b1v = b1[cc], b2v = b2[cc];
      const int h = cc >> 6, d = cc & 63;
      if constexpr (MODE == 0) {
#pragma unroll
        for (int j = 0; j < 4; ++j) {
          const int r = r0 + j;
          const float x = b2f(G1[(size_t)r * N + cc]) + b1v;
          const float y = acc[mf][nf][j] + b2v;
          const float v = (x / (1.f + __expf(-x))) * y * scale;
          const int bb = r >> 11, s = r & 2047;
          out[((size_t)(bb * 16 + h) * 2048 + s) * 64 + d] = f2b(v);
        }
      } else {
        u16x4 w;
#pragma unroll
        for (int j = 0; j < 4; ++j) {
          const int r = r0 + j;
          const float x = b2f(G1[(size_t)r * N + cc]) + b1v;
          const float y = acc[mf][nf][j] + b2v;
          w[j] = f2b((x / (1.f + __expf(-x))) * y);
        }
        const int bb = r0 >> 11, s = r0 & 2047;   // r0 % 4 == 0
        *(u16x4*)(out + ((size_t)(bb * 16 + h) * 64 + d) * 2048 + s) = w;
      }
    }
  }
}

// ---------------------------------------------------------------------------
// Causal flash attention, pair-balanced + 2-phase pipelined.
// Q pre-scaled by 0.125*log2e.  Q,K: [BH,S,64].  Vt: [BH,64,S].
// grid (8,64): block x does q-blocks {x, 15-x} (34 k-tiles, uniform).
// K/V double-buffered in LDS via global_load_lds; 1 barrier per k-tile.
__global__ __launch_bounds__(256, 2) void attn_fwd(
    const u16* __restrict__ Q, const u16* __restrict__ Kk,
    const u16* __restrict__ Vt, u16* __restrict__ O)
{
  __shared__ char smem[49152];           // 2 x (K 8K | V 8K) + Pw 16K
  char* Pw = smem + 32768 + (threadIdx.x >> 6) * 4096;  // per-wave [32 q][128B]
  const int t = threadIdx.x;
  const int lane = t & 63, wid = t >> 6;
  const int lg = lane >> 4, lc = lane & 15;
  const int bh = blockIdx.y;
  const int b = bh >> 4, h = bh & 15;
  const f32x4 fz = {0.f, 0.f, 0.f, 0.f};

  auto STAGE = [&](int buf, int kt) {
    const int kbase = kt << 6;
    char* Kb = smem + buf * 16384;
    char* Vb = Kb + 8192;
#pragma unroll
    for (int p = 0; p < 4; ++p) {
      const int idx = wid * 4 + p;       // 0..15 (8 K-chunks, 8 V-chunks)
      const int rb = (idx & 7) * 8;
      const int row = rb + (lane >> 3);
      const int ce = (((lane & 7) << 4) ^ ((row & 7) << 4)) >> 1;
      if (idx < 8)
        gload16(Kk + ((size_t)bh * 2048 + kbase + row) * 64 + ce, Kb + rb * 128);
      else
        gload16(Vt + ((size_t)bh * 64 + row) * 2048 + kbase + ce, Vb + rb * 128);
    }
  };

  for (int pass = 0; pass < 2; ++pass) {
    const int qblk = pass ? (15 - (int)blockIdx.x) : (int)blockIdx.x;
    const int q0 = qblk * 128;
    const int qw = q0 + wid * 32;        // wave's first q row

    bf16x8 qf[2][2];                     // Q A-frags in regs for all tiles
#pragma unroll
    for (int mf = 0; mf < 2; ++mf)
#pragma unroll
      for (int kh = 0; kh < 2; ++kh) {
        const int r = qw + mf * 16 + lc;
        qf[mf][kh] = *(const bf16x8*)(Q + ((size_t)bh * 2048 + r) * 64 + kh * 32 + lg * 8);
      }

    f32x4 o[2][4];
    float mrow[2][4], lrow[2][4];
#pragma unroll
    for (int mf = 0; mf < 2; ++mf) {
#pragma unroll
      for (int dn = 0; dn < 4; ++dn) o[mf][dn] = fz;
#pragma unroll
      for (int j = 0; j < 4; ++j) { mrow[mf][j] = -1e30f; lrow[mf][j] = 0.f; }
    }

    const int nt = 2 * qblk + 2;
    STAGE(0, 0);
    __syncthreads();
    for (int kt = 0; kt < nt; ++kt) {
      const int cur = kt & 1;
      if (kt + 1 < nt) STAGE(cur ^ 1, kt + 1);   // prefetch next tile
      const int kbase = kt << 6;
      const char* Ks = smem + cur * 16384;
      const char* Vs = Ks + 8192;
      if (kbase <= qw + 31) {            // wave has unmasked work here
        // --- QK^T ---
        f32x4 sf[2][4];
#pragma unroll
        for (int mf = 0; mf < 2; ++mf)
#pragma unroll
          for (int nf = 0; nf < 4; ++nf) sf[mf][nf] = fz;
        __builtin_amdgcn_s_setprio(1);
#pragma unroll
        for (int kh = 0; kh < 2; ++kh) {
          bf16x8 kb[4];
#pragma unroll
          for (int nf = 0; nf < 4; ++nf) {
            const int r = nf * 16 + lc;
            kb[nf] = *(const bf16x8*)(Ks + r * 128 + ((kh * 64 + (lg << 4)) ^ ((r & 7) << 4)));
          }
#pragma unroll
          for (int mf = 0; mf < 2; ++mf)
#pragma unroll
            for (int nf = 0; nf < 4; ++nf)
              sf[mf][nf] = mfma16(qf[mf][kh], kb[nf], sf[mf][nf]);
        }
        __builtin_amdgcn_s_setprio(0);
        // --- causal mask (diagonal-overlap tiles only) ---
        if (kbase + 63 > qw) {
#pragma unroll
          for (int mf = 0; mf < 2; ++mf)
#pragma unroll
            for (int nf = 0; nf < 4; ++nf)
#pragma unroll
              for (int j = 0; j < 4; ++j) {
                const int qr = qw + mf * 16 + (lg << 2) + j;
                const int kc = kbase + nf * 16 + lc;
                if (kc > qr) sf[mf][nf][j] = -1e30f;
              }
        }
        // --- online softmax (exp2 domain, defer-rescale) ---
#pragma unroll
        for (int mf = 0; mf < 2; ++mf) {
          float pm[4];
#pragma unroll
          for (int j = 0; j < 4; ++j)
            pm[j] = fmaxf(fmaxf(sf[mf][0][j], sf[mf][1][j]), fmaxf(sf[mf][2][j], sf[mf][3][j]));
#pragma unroll
          for (int dd = 1; dd <= 8; dd <<= 1)
#pragma unroll
            for (int j = 0; j < 4; ++j)
              pm[j] = fmaxf(pm[j], __shfl_xor(pm[j], dd, 64));
          bool grow = false;
#pragma unroll
          for (int j = 0; j < 4; ++j) grow |= (pm[j] > mrow[mf][j]);
          if (__any(grow)) {
            float scj[4];
#pragma unroll
            for (int j = 0; j < 4; ++j) {
              const float mn = fmaxf(mrow[mf][j], pm[j]);
              scj[j] = exp2f(mrow[mf][j] - mn);
              mrow[mf][j] = mn;
              lrow[mf][j] *= scj[j];
            }
#pragma unroll
            for (int dn = 0; dn < 4; ++dn)
#pragma unroll
              for (int j = 0; j < 4; ++j)
                o[mf][dn][j] *= scj[j];
          }
          float rsum[4] = {0.f, 0.f, 0.f, 0.f};
#pragma unroll
          for (int nf = 0; nf < 4; ++nf)
#pragma unroll
            for (int j = 0; j < 4; ++j) {
              const float p = exp2f(sf[mf][nf][j] - mrow[mf][j]);
              sf[mf][nf][j] = p;
              rsum[j] += p;
            }
#pragma unroll
          for (int dd = 1; dd <= 8; dd <<= 1)
#pragma unroll
            for (int j = 0; j < 4; ++j)
              rsum[j] += __shfl_xor(rsum[j], dd, 64);
#pragma unroll
          for (int j = 0; j < 4; ++j) lrow[mf][j] += rsum[j];
          // write P (C-frag layout) into swizzled per-wave LDS
#pragma unroll
          for (int nf = 0; nf < 4; ++nf)
#pragma unroll
            for (int j = 0; j < 4; ++j) {
              const int pr = mf * 16 + (lg << 2) + j;
              const int pcb = (nf * 16 + lc) << 1;
              *(u16*)(Pw + pr * 128 + (pcb ^ ((pr & 7) << 4))) = f2b(sf[mf][nf][j]);
            }
        }
        // --- PV: A = P (from LDS), B = V^T rows (contiguous k) ---
        __builtin_amdgcn_s_setprio(1);
#pragma unroll
        for (int kh = 0; kh < 2; ++kh) {
          bf16x8 pa[2];
#pragma unroll
          for (int mf = 0; mf < 2; ++mf) {
            const int pr = mf * 16 + lc;
            pa[mf] = *(const bf16x8*)(Pw + pr * 128 + ((kh * 64 + (lg << 4)) ^ ((pr & 7) << 4)));
          }
#pragma unroll
          for (int dn = 0; dn < 4; ++dn) {
            const int vr = dn * 16 + lc;
            const bf16x8 vb = *(const bf16x8*)(Vs + vr * 128 + ((kh * 64 + (lg << 4)) ^ ((vr & 7) << 4)));
#pragma unroll
            for (int mf = 0; mf < 2; ++mf)
              o[mf][dn] = mfma16(pa[mf], vb, o[mf][dn]);
          }
        }
        __builtin_amdgcn_s_setprio(0);
      }
      __syncthreads();                   // next buffer staged; cur reusable
    }
    // epilogue: O[b, s, h*64+d] = o / l
#pragma unroll
    for (int mf = 0; mf < 2; ++mf)
#pragma unroll
      for (int dn = 0; dn < 4; ++dn)
#pragma unroll
        for (int j = 0; j < 4; ++j) {
          const int s = qw + mf * 16 + (lg << 2) + j;
          const int d = dn * 16 + lc;
          const float v = o[mf][dn][j] / lrow[mf][j];
          O[((size_t)(b * 2048 + s) * 16 + h) * 64 + d] = f2b(v);
        }
  }
}

// ---------------------------------------------------------------------------
extern "C" void kernel_launch(void* const* d_in, const int* in_sizes, int n_in,
                              void* d_out, int out_size, void* d_ws, size_t ws_size,
                              hipStream_t stream)
{
  (void)in_sizes; (void)n_in; (void)out_size; (void)ws_size;
  const float* xq  = (const float*)d_in[0];
  const float* xk  = (const float*)d_in[1];
  const float* xv  = (const float*)d_in[2];
  // d_in[3] = causal mask -- hardcoded in attn_fwd
  const float* wq1 = (const float*)d_in[4];
  const float* bq1 = (const float*)d_in[5];
  const float* wq2 = (const float*)d_in[6];
  const float* bq2 = (const float*)d_in[7];
  const float* wk1 = (const float*)d_in[8];
  const float* bk1 = (const float*)d_in[9];
  const float* wk2 = (const float*)d_in[10];
  const float* bk2 = (const float*)d_in[11];
  const float* wv1 = (const float*)d_in[12];
  const float* bv1 = (const float*)d_in[13];
  const float* wv2 = (const float*)d_in[14];
  const float* bv2 = (const float*)d_in[15];
  const float* wo  = (const float*)d_in[16];
  const float* bo  = (const float*)d_in[17];

  // Workspace (94 MB total, same as prior round):
  // WB 14MB | XB/AO 16MB | G1 16MB | QB 16MB | KB 16MB | VT 16MB
  char* ws = (char*)d_ws;
  u16* WB = (u16*)ws;
  u16* XB = (u16*)(ws + 14680064);       // converted activation; AO after V-proj
  u16* G1 = (u16*)(ws + 31457280);
  u16* QB = (u16*)(ws + 48234496);
  u16* KB = (u16*)(ws + 65011712);
  u16* VT = (u16*)(ws + 81788928);
  u16* AO = XB;                          // attn out aliases dead XB

  P7 p7 = {{wq1, wq2, wk1, wk2, wv1, wv2, wo}};
  cvt_w<<<dim3(512, 7), 256, 0, stream>>>(p7, WB);

  const dim3 gg(8, 64);   // (N/128, M/128)
  const float QSCALE = 0.125f * 1.44269504088896f;  // 1/sqrt(dk) * log2(e)
  // Q projection
  cvt_x<<<4096, 256, 0, stream>>>(xq, XB);
  gemm_bt<true, false><<<gg, 256, 0, stream>>>(XB, WB + 0 * 1048576, nullptr, G1, 1024, 1024);
  gemm_merge<0><<<gg, 256, 0, stream>>>(XB, WB + 1 * 1048576, G1, bq1, bq2, QB, QSCALE, 1024, 1024);
  // K projection
  cvt_x<<<4096, 256, 0, stream>>>(xk, XB);
  gemm_bt<true, false><<<gg, 256, 0, stream>>>(XB, WB + 2 * 1048576, nullptr, G1, 1024, 1024);
  gemm_merge<0><<<gg, 256, 0, stream>>>(XB, WB + 3 * 1048576, G1, bk1, bk2, KB, 1.0f, 1024, 1024);
  // V projection (transposed output)
  cvt_x<<<4096, 256, 0, stream>>>(xv, XB);
  gemm_bt<true, false><<<gg, 256, 0, stream>>>(XB, WB + 4 * 1048576, nullptr, G1, 1024, 1024);
  gemm_merge<1><<<gg, 256, 0, stream>>>(XB, WB + 5 * 1048576, G1, bv1, bv2, VT, 1.0f, 1024, 1024);
  // attention (pair-balanced, pipelined)
  attn_fwd<<<dim3(8, 64), 256, 0, stream>>>(QB, KB, VT, AO);
  // output projection
  gemm_bt<false, true><<<gg, 256, 0, stream>>>(AO, WB + 6 * 1048576, bo, (float*)d_out, 1024, 1024);
}

// Round 4
// 336.750 us; speedup vs baseline: 1.5828x; 1.0471x over previous
//
#include <hip/hip_runtime.h>

// B=4, S=2048, D_MODEL=1024, H=16, DK=64.  M = B*S = 8192.
// Pipeline: cvt weights -> per projection {cvt act, GEMM1, GEMM2+merge}
// -> causal flash attention (64-q chunks, pair-balanced, XCD-swizzled,
//    4 blocks/CU) -> out GEMM.
// All GEMM/attn staging via global_load_lds (dwordx4), dbuf + 1 barrier/step.

typedef __bf16 bf16;
typedef bf16 bf16x8 __attribute__((ext_vector_type(8)));
typedef float f32x4 __attribute__((ext_vector_type(4)));
typedef unsigned short u16;
typedef unsigned int u32;
typedef u16 u16x8 __attribute__((ext_vector_type(8)));
typedef u16 u16x4 __attribute__((ext_vector_type(4)));

#define DEVI static __device__ __forceinline__

DEVI u16 f2b(float f) {                    // f32 -> bf16 bits, RNE
  union { float f; u32 u; } v; v.f = f;
  u32 r = v.u + 0x7FFFu + ((v.u >> 16) & 1u);
  return (u16)(r >> 16);
}
DEVI float b2f(u16 b) {
  union { u32 u; float f; } v; v.u = ((u32)b) << 16; return v.f;
}
DEVI f32x4 mfma16(bf16x8 a, bf16x8 b, f32x4 c) {
  return __builtin_amdgcn_mfma_f32_16x16x32_bf16(a, b, c, 0, 0, 0);
}
// async global -> LDS, 16B per lane.  LDS dest = wave-uniform base + lane*16.
DEVI void gload16(const void* g, void* l) {
  __builtin_amdgcn_global_load_lds(
      (const __attribute__((address_space(1))) void*)g,
      (__attribute__((address_space(3))) void*)l, 16, 0, 0);
}

// ---------------------------------------------------------------------------
// Weight convert: 7 matrices of 1024x1024 f32 -> bf16.
struct P7 { const float* p[7]; };

__global__ void cvt_w(P7 in, u16* __restrict__ out) {
  const int which = blockIdx.y;
  const float* src = in.p[which];
  u16* dst = out + (size_t)which * 1048576;
  const int i = blockIdx.x * 256 + threadIdx.x;     // grid.x = 512
  const f32x4 a = ((const f32x4*)src)[i * 2];
  const f32x4 b = ((const f32x4*)src)[i * 2 + 1];
  u16x8 w;
#pragma unroll
  for (int j = 0; j < 4; ++j) { w[j] = f2b(a[j]); w[4 + j] = f2b(b[j]); }
  ((u16x8*)dst)[i] = w;
}

// Activation convert: 8192x1024 f32 -> bf16 (one matrix per launch).
__global__ void cvt_x(const float* __restrict__ src, u16* __restrict__ dst) {
  const int i = blockIdx.x * 256 + threadIdx.x;     // grid.x = 4096
  const f32x4 a = ((const f32x4*)src)[i * 2];
  const f32x4 b = ((const f32x4*)src)[i * 2 + 1];
  u16x8 w;
#pragma unroll
  for (int j = 0; j < 4; ++j) { w[j] = f2b(a[j]); w[4 + j] = f2b(b[j]); }
  ((u16x8*)dst)[i] = w;
}

// ---------------------------------------------------------------------------
// GEMM: C[M,N] = A[M,K]*B[N,K]^T, bf16 in.  BM=BN=128, BK=64, 4 waves (2x2).
// global_load_lds staging, double-buffered, 1 barrier/K-step.
// Source col pre-swizzled, LDS linear, frag reads XOR-swizzled.
template<bool OUT_BF16, bool BIAS>
__global__ __launch_bounds__(256, 2) void gemm_bt(
    const u16* __restrict__ Ap, const u16* __restrict__ Bp,
    const float* __restrict__ bias, void* __restrict__ Cp,
    int N, int K)
{
  __shared__ char smem[65536];                 // 2 x (As 16K | Bs 16K)
  const int t = threadIdx.x;
  const int lane = t & 63;
  const int lg = lane >> 4, lc = lane & 15;
  const int wid = t >> 6;
  const int wr = (wid >> 1) * 64, wc = (wid & 1) * 64;
  const int m0 = blockIdx.y * 128, n0 = blockIdx.x * 128;
  const int srow = lane >> 3;                  // 0..7 within 8-row chunk
  const int scolb = (lane & 7) << 4;           // byte col 0..112

  const f32x4 fz = {0.f, 0.f, 0.f, 0.f};
  f32x4 acc[4][4];
#pragma unroll
  for (int i = 0; i < 4; ++i)
#pragma unroll
    for (int j = 0; j < 4; ++j) acc[i][j] = fz;

  const int nk = K >> 6;
  auto STAGE = [&](int buf, int kt) {
    const int k0 = kt << 6;
    char* As = smem + buf * 32768;
    char* Bs = As + 16384;
#pragma unroll
    for (int p = 0; p < 4; ++p) {
      const int rb = wid * 32 + p * 8;         // wave-uniform chunk base
      const int row = rb + srow;
      const int ce = (scolb ^ ((row & 7) << 4)) >> 1;   // element col
      gload16(Ap + (size_t)(m0 + row) * K + k0 + ce, As + rb * 128);
      gload16(Bp + (size_t)(n0 + row) * K + k0 + ce, Bs + rb * 128);
    }
  };

  STAGE(0, 0);
  __syncthreads();                             // drains stage 0
  for (int kt = 0; kt < nk; ++kt) {
    const int cur = kt & 1;
    if (kt + 1 < nk) STAGE(cur ^ 1, kt + 1);   // issue next tile early
    const char* As = smem + cur * 32768;
    const char* Bs = As + 16384;
#pragma unroll
    for (int kh = 0; kh < 2; ++kh) {
      bf16x8 af[4], bfr[4];
#pragma unroll
      for (int mf = 0; mf < 4; ++mf) {
        const int r = wr + mf * 16 + lc;
        af[mf] = *(const bf16x8*)(As + r * 128 + ((kh * 64 + (lg << 4)) ^ ((r & 7) << 4)));
      }
#pragma unroll
      for (int nf = 0; nf < 4; ++nf) {
        const int r = wc + nf * 16 + lc;
        bfr[nf] = *(const bf16x8*)(Bs + r * 128 + ((kh * 64 + (lg << 4)) ^ ((r & 7) << 4)));
      }
#pragma unroll
      for (int mf = 0; mf < 4; ++mf)
#pragma unroll
        for (int nf = 0; nf < 4; ++nf)
          acc[mf][nf] = mfma16(af[mf], bfr[nf], acc[mf][nf]);
    }
    __syncthreads();                           // next buffer ready; LDS reusable
  }
  // epilogue: C/D frag row = (lane>>4)*4 + j, col = lane&15
#pragma unroll
  for (int mf = 0; mf < 4; ++mf) {
#pragma unroll
    for (int nf = 0; nf < 4; ++nf) {
      const int r0 = m0 + wr + mf * 16 + (lg << 2);
      const int cc = n0 + wc + nf * 16 + lc;
      float bv = 0.f;
      if constexpr (BIAS) bv = bias[cc];
#pragma unroll
      for (int j = 0; j < 4; ++j) {
        const float vv = acc[mf][nf][j] + bv;
        if constexpr (OUT_BF16) ((u16*)Cp)[(size_t)(r0 + j) * N + cc] = f2b(vv);
        else                    ((float*)Cp)[(size_t)(r0 + j) * N + cc] = vv;
      }
    }
  }
}

// ---------------------------------------------------------------------------
// GEMM2 + merge: C2 = A*W2^T; out = silu(G1+b1)*(C2+b2)*scale.
// MODE 0: write [B,H,S,64] (Q/K).  MODE 1: write V^T [B,H,64,S].
template<int MODE>
__global__ __launch_bounds__(256, 2) void gemm_merge(
    const u16* __restrict__ Ap, const u16* __restrict__ Bp,
    const u16* __restrict__ G1, const float* __restrict__ b1,
    const float* __restrict__ b2, u16* __restrict__ out,
    float scale, int N, int K)
{
  __shared__ char smem[65536];
  const int t = threadIdx.x;
  const int lane = t & 63;
  const int lg = lane >> 4, lc = lane & 15;
  const int wid = t >> 6;
  const int wr = (wid >> 1) * 64, wc = (wid & 1) * 64;
  const int m0 = blockIdx.y * 128, n0 = blockIdx.x * 128;
  const int srow = lane >> 3;
  const int scolb = (lane & 7) << 4;

  const f32x4 fz = {0.f, 0.f, 0.f, 0.f};
  f32x4 acc[4][4];
#pragma unroll
  for (int i = 0; i < 4; ++i)
#pragma unroll
    for (int j = 0; j < 4; ++j) acc[i][j] = fz;

  const int nk = K >> 6;
  auto STAGE = [&](int buf, int kt) {
    const int k0 = kt << 6;
    char* As = smem + buf * 32768;
    char* Bs = As + 16384;
#pragma unroll
    for (int p = 0; p < 4; ++p) {
      const int rb = wid * 32 + p * 8;
      const int row = rb + srow;
      const int ce = (scolb ^ ((row & 7) << 4)) >> 1;
      gload16(Ap + (size_t)(m0 + row) * K + k0 + ce, As + rb * 128);
      gload16(Bp + (size_t)(n0 + row) * K + k0 + ce, Bs + rb * 128);
    }
  };

  STAGE(0, 0);
  __syncthreads();
  for (int kt = 0; kt < nk; ++kt) {
    const int cur = kt & 1;
    if (kt + 1 < nk) STAGE(cur ^ 1, kt + 1);
    const char* As = smem + cur * 32768;
    const char* Bs = As + 16384;
#pragma unroll
    for (int kh = 0; kh < 2; ++kh) {
      bf16x8 af[4], bfr[4];
#pragma unroll
      for (int mf = 0; mf < 4; ++mf) {
        const int r = wr + mf * 16 + lc;
        af[mf] = *(const bf16x8*)(As + r * 128 + ((kh * 64 + (lg << 4)) ^ ((r & 7) << 4)));
      }
#pragma unroll
      for (int nf = 0; nf < 4; ++nf) {
        const int r = wc + nf * 16 + lc;
        bfr[nf] = *(const bf16x8*)(Bs + r * 128 + ((kh * 64 + (lg << 4)) ^ ((r & 7) << 4)));
      }
#pragma unroll
      for (int mf = 0; mf < 4; ++mf)
#pragma unroll
        for (int nf = 0; nf < 4; ++nf)
          acc[mf][nf] = mfma16(af[mf], bfr[nf], acc[mf][nf]);
    }
    __syncthreads();
  }
  // merge epilogue
#pragma unroll
  for (int mf = 0; mf < 4; ++mf) {
#pragma unroll
    for (int nf = 0; nf < 4; ++nf) {
      const int r0 = m0 + wr + mf * 16 + (lg << 2);
      const int cc = n0 + wc + nf * 16 + lc;
      const float b1v = b1[cc], b2v = b2[cc];
      const int h = cc >> 6, d = cc & 63;
      if constexpr (MODE == 0) {
#pragma unroll
        for (int j = 0; j < 4; ++j) {
          const int r = r0 + j;
          const float x = b2f(G1[(size_t)r * N + cc]) + b1v;
          const float y = acc[mf][nf][j] + b2v;
          const float v = (x / (1.f + __expf(-x))) * y * scale;
          const int bb = r >> 11, s = r & 2047;
          out[((size_t)(bb * 16 + h) * 2048 + s) * 64 + d] = f2b(v);
        }
      } else {
        u16x4 w;
#pragma unroll
        for (int j = 0; j < 4; ++j) {
          const int r = r0 + j;
          const float x = b2f(G1[(size_t)r * N + cc]) + b1v;
          const float y = acc[mf][nf][j] + b2v;
          w[j] = f2b((x / (1.f + __expf(-x))) * y);
        }
        const int bb = r0 >> 11, s = r0 & 2047;   // r0 % 4 == 0
        *(u16x4*)(out + ((size_t)(bb * 16 + h) * 64 + d) * 2048 + s) = w;
      }
    }
  }
}

// ---------------------------------------------------------------------------
// Causal flash attention.  64-q chunks, pair-balanced, XCD-swizzled.
// Q pre-scaled by 0.125*log2e (exp2 domain).  Q,K: [BH,S,64].  Vt: [BH,64,S].
// grid (16,64) = 1024 blocks = 4 blocks/CU.  Block: 4 waves x 16 q-rows = 64 q.
// Pass 0: q-chunk qi; pass 1: q-chunk 31-qi  -> 33 k-tiles/block, uniform;
// every wave computes every tile (no intra-block skip imbalance).
// XCD swizzle: all 16 q-chunks of one bh land on one XCD (K/V L2-resident).
// K/V double-buffered in LDS via global_load_lds; 1 barrier per k-tile.
__global__ __launch_bounds__(256, 4) void attn_fwd(
    const u16* __restrict__ Q, const u16* __restrict__ Kk,
    const u16* __restrict__ Vt, u16* __restrict__ O)
{
  __shared__ char smem[40960];           // 2 x (K 8K | V 8K) + Pw 8K
  char* Pw = smem + 32768 + (threadIdx.x >> 6) * 2048;  // per-wave [16 q][128B]
  const int t = threadIdx.x;
  const int lane = t & 63, wid = t >> 6;
  const int lg = lane >> 4, lc = lane & 15;
  // bijective XCD swizzle: same-bh blocks share (flat & 7) -> same XCD
  const int flat = blockIdx.y * 16 + blockIdx.x;
  const int fl2 = (flat & 7) * 128 + (flat >> 3);
  const int qi = fl2 & 15;
  const int bh = fl2 >> 4;
  const int b = bh >> 4, h = bh & 15;
  const f32x4 fz = {0.f, 0.f, 0.f, 0.f};

  auto STAGE = [&](int buf, int kt) {
    const int kbase = kt << 6;
    char* Kb = smem + buf * 16384;
    char* Vb = Kb + 8192;
#pragma unroll
    for (int p = 0; p < 4; ++p) {
      const int idx = wid * 4 + p;       // 0..15 (8 K-chunks, 8 V-chunks)
      const int rb = (idx & 7) * 8;
      const int row = rb + (lane >> 3);
      const int ce = (((lane & 7) << 4) ^ ((row & 7) << 4)) >> 1;
      if (idx < 8)
        gload16(Kk + ((size_t)bh * 2048 + kbase + row) * 64 + ce, Kb + rb * 128);
      else
        gload16(Vt + ((size_t)bh * 64 + row) * 2048 + kbase + ce, Vb + rb * 128);
    }
  };

  for (int pass = 0; pass < 2; ++pass) {
    const int qc = pass ? (31 - qi) : qi;
    const int q0 = qc * 64;
    const int qw = q0 + wid * 16;        // wave's first q row

    bf16x8 qf[2];                        // Q A-frags in regs for all tiles
#pragma unroll
    for (int kh = 0; kh < 2; ++kh) {
      const int r = qw + lc;
      qf[kh] = *(const bf16x8*)(Q + ((size_t)bh * 2048 + r) * 64 + kh * 32 + lg * 8);
    }

    f32x4 o[4];
    float mrow[4], lrow[4];
#pragma unroll
    for (int dn = 0; dn < 4; ++dn) o[dn] = fz;
#pragma unroll
    for (int j = 0; j < 4; ++j) { mrow[j] = -1e30f; lrow[j] = 0.f; }

    const int nt = qc + 1;
    STAGE(0, 0);
    __syncthreads();
    for (int kt = 0; kt < nt; ++kt) {
      const int cur = kt & 1;
      if (kt + 1 < nt) STAGE(cur ^ 1, kt + 1);   // prefetch next tile
      const int kbase = kt << 6;
      const char* Ks = smem + cur * 16384;
      const char* Vs = Ks + 8192;
      // --- QK^T ---
      f32x4 sf[4];
#pragma unroll
      for (int nf = 0; nf < 4; ++nf) sf[nf] = fz;
      __builtin_amdgcn_s_setprio(1);
#pragma unroll
      for (int kh = 0; kh < 2; ++kh) {
        bf16x8 kb[4];
#pragma unroll
        for (int nf = 0; nf < 4; ++nf) {
          const int r = nf * 16 + lc;
          kb[nf] = *(const bf16x8*)(Ks + r * 128 + ((kh * 64 + (lg << 4)) ^ ((r & 7) << 4)));
        }
#pragma unroll
        for (int nf = 0; nf < 4; ++nf)
          sf[nf] = mfma16(qf[kh], kb[nf], sf[nf]);
      }
      __builtin_amdgcn_s_setprio(0);
      // --- causal mask (diagonal-overlap tiles only) ---
      if (kbase + 63 > qw) {
#pragma unroll
        for (int nf = 0; nf < 4; ++nf)
#pragma unroll
          for (int j = 0; j < 4; ++j) {
            const int qr = qw + (lg << 2) + j;
            const int kc = kbase + nf * 16 + lc;
            if (kc > qr) sf[nf][j] = -1e30f;
          }
      }
      // --- online softmax (exp2 domain, defer-rescale) ---
      {
        float pm[4];
#pragma unroll
        for (int j = 0; j < 4; ++j)
          pm[j] = fmaxf(fmaxf(sf[0][j], sf[1][j]), fmaxf(sf[2][j], sf[3][j]));
#pragma unroll
        for (int dd = 1; dd <= 8; dd <<= 1)
#pragma unroll
          for (int j = 0; j < 4; ++j)
            pm[j] = fmaxf(pm[j], __shfl_xor(pm[j], dd, 64));
        bool grow = false;
#pragma unroll
        for (int j = 0; j < 4; ++j) grow |= (pm[j] > mrow[j]);
        if (__any(grow)) {
          float scj[4];
#pragma unroll
          for (int j = 0; j < 4; ++j) {
            const float mn = fmaxf(mrow[j], pm[j]);
            scj[j] = exp2f(mrow[j] - mn);
            mrow[j] = mn;
            lrow[j] *= scj[j];
          }
#pragma unroll
          for (int dn = 0; dn < 4; ++dn)
#pragma unroll
            for (int j = 0; j < 4; ++j)
              o[dn][j] *= scj[j];
        }
        float rsum[4] = {0.f, 0.f, 0.f, 0.f};
#pragma unroll
        for (int nf = 0; nf < 4; ++nf)
#pragma unroll
          for (int j = 0; j < 4; ++j) {
            const float p = exp2f(sf[nf][j] - mrow[j]);
            sf[nf][j] = p;
            rsum[j] += p;
          }
#pragma unroll
        for (int dd = 1; dd <= 8; dd <<= 1)
#pragma unroll
          for (int j = 0; j < 4; ++j)
            rsum[j] += __shfl_xor(rsum[j], dd, 64);
#pragma unroll
        for (int j = 0; j < 4; ++j) lrow[j] += rsum[j];
        // write P (C-frag layout) into swizzled per-wave LDS
#pragma unroll
        for (int nf = 0; nf < 4; ++nf)
#pragma unroll
          for (int j = 0; j < 4; ++j) {
            const int pr = (lg << 2) + j;
            const int pcb = (nf * 16 + lc) << 1;
            *(u16*)(Pw + pr * 128 + (pcb ^ ((pr & 7) << 4))) = f2b(sf[nf][j]);
          }
      }
      // --- PV: A = P (from LDS), B = V^T rows (contiguous k) ---
      __builtin_amdgcn_s_setprio(1);
#pragma unroll
      for (int kh = 0; kh < 2; ++kh) {
        const int pr = lc;
        const bf16x8 pa = *(const bf16x8*)(Pw + pr * 128 + ((kh * 64 + (lg << 4)) ^ ((pr & 7) << 4)));
#pragma unroll
        for (int dn = 0; dn < 4; ++dn) {
          const int vr = dn * 16 + lc;
          const bf16x8 vb = *(const bf16x8*)(Vs + vr * 128 + ((kh * 64 + (lg << 4)) ^ ((vr & 7) << 4)));
          o[dn] = mfma16(pa, vb, o[dn]);
        }
      }
      __builtin_amdgcn_s_setprio(0);
      __syncthreads();                   // next buffer staged; cur reusable
    }
    // epilogue: O[b, s, h*64+d] = o / l
#pragma unroll
    for (int dn = 0; dn < 4; ++dn)
#pragma unroll
      for (int j = 0; j < 4; ++j) {
        const int s = qw + (lg << 2) + j;
        const int d = dn * 16 + lc;
        const float v = o[dn][j] / lrow[j];
        O[((size_t)(b * 2048 + s) * 16 + h) * 64 + d] = f2b(v);
      }
  }
}

// ---------------------------------------------------------------------------
extern "C" void kernel_launch(void* const* d_in, const int* in_sizes, int n_in,
                              void* d_out, int out_size, void* d_ws, size_t ws_size,
                              hipStream_t stream)
{
  (void)in_sizes; (void)n_in; (void)out_size; (void)ws_size;
  const float* xq  = (const float*)d_in[0];
  const float* xk  = (const float*)d_in[1];
  const float* xv  = (const float*)d_in[2];
  // d_in[3] = causal mask -- hardcoded in attn_fwd
  const float* wq1 = (const float*)d_in[4];
  const float* bq1 = (const float*)d_in[5];
  const float* wq2 = (const float*)d_in[6];
  const float* bq2 = (const float*)d_in[7];
  const float* wk1 = (const float*)d_in[8];
  const float* bk1 = (const float*)d_in[9];
  const float* wk2 = (const float*)d_in[10];
  const float* bk2 = (const float*)d_in[11];
  const float* wv1 = (const float*)d_in[12];
  const float* bv1 = (const float*)d_in[13];
  const float* wv2 = (const float*)d_in[14];
  const float* bv2 = (const float*)d_in[15];
  const float* wo  = (const float*)d_in[16];
  const float* bo  = (const float*)d_in[17];

  // Workspace (94 MB total):
  // WB 14MB | XB/AO 16MB | G1 16MB | QB 16MB | KB 16MB | VT 16MB
  char* ws = (char*)d_ws;
  u16* WB = (u16*)ws;
  u16* XB = (u16*)(ws + 14680064);       // converted activation; AO after V-proj
  u16* G1 = (u16*)(ws + 31457280);
  u16* QB = (u16*)(ws + 48234496);
  u16* KB = (u16*)(ws + 65011712);
  u16* VT = (u16*)(ws + 81788928);
  u16* AO = XB;                          // attn out aliases dead XB

  P7 p7 = {{wq1, wq2, wk1, wk2, wv1, wv2, wo}};
  cvt_w<<<dim3(512, 7), 256, 0, stream>>>(p7, WB);

  const dim3 gg(8, 64);   // (N/128, M/128)
  const float QSCALE = 0.125f * 1.44269504088896f;  // 1/sqrt(dk) * log2(e)
  // Q projection
  cvt_x<<<4096, 256, 0, stream>>>(xq, XB);
  gemm_bt<true, false><<<gg, 256, 0, stream>>>(XB, WB + 0 * 1048576, nullptr, G1, 1024, 1024);
  gemm_merge<0><<<gg, 256, 0, stream>>>(XB, WB + 1 * 1048576, G1, bq1, bq2, QB, QSCALE, 1024, 1024);
  // K projection
  cvt_x<<<4096, 256, 0, stream>>>(xk, XB);
  gemm_bt<true, false><<<gg, 256, 0, stream>>>(XB, WB + 2 * 1048576, nullptr, G1, 1024, 1024);
  gemm_merge<0><<<gg, 256, 0, stream>>>(XB, WB + 3 * 1048576, G1, bk1, bk2, KB, 1.0f, 1024, 1024);
  // V projection (transposed output)
  cvt_x<<<4096, 256, 0, stream>>>(xv, XB);
  gemm_bt<true, false><<<gg, 256, 0, stream>>>(XB, WB + 4 * 1048576, nullptr, G1, 1024, 1024);
  gemm_merge<1><<<gg, 256, 0, stream>>>(XB, WB + 5 * 1048576, G1, bv1, bv2, VT, 1.0f, 1024, 1024);
  // attention (pair-balanced, XCD-swizzled, 4 blocks/CU)
  attn_fwd<<<dim3(16, 64), 256, 0, stream>>>(QB, KB, VT, AO);
  // output projection
  gemm_bt<false, true><<<gg, 256, 0, stream>>>(AO, WB + 6 * 1048576, bo, (float*)d_out, 1024, 1024);
}

// Round 5
// 262.226 us; speedup vs baseline: 2.0327x; 1.2842x over previous
//
#include <hip/hip_runtime.h>

// B=4, S=2048, D_MODEL=1024, H=16, DK=64.  M = B*S = 8192.
// Pipeline: cvt weights (W1/W2 interleaved "Wcat") -> per projection
// {cvt act, fused dual-gate swiglu GEMM (BM=256)} -> causal flash attention
// (ones-MFMA rowsum + THR defer-max) -> output GEMM (BM=256).

typedef __bf16 bf16;
typedef bf16 bf16x8 __attribute__((ext_vector_type(8)));
typedef float f32x4 __attribute__((ext_vector_type(4)));
typedef unsigned short u16;
typedef unsigned int u32;
typedef u16 u16x8 __attribute__((ext_vector_type(8)));
typedef u16 u16x4 __attribute__((ext_vector_type(4)));

#define DEVI static __device__ __forceinline__

DEVI u16 f2b(float f) {                    // f32 -> bf16 bits, RNE
  union { float f; u32 u; } v; v.f = f;
  u32 r = v.u + 0x7FFFu + ((v.u >> 16) & 1u);
  return (u16)(r >> 16);
}
DEVI f32x4 mfma16(bf16x8 a, bf16x8 b, f32x4 c) {
  return __builtin_amdgcn_mfma_f32_16x16x32_bf16(a, b, c, 0, 0, 0);
}
// async global -> LDS, 16B per lane.  LDS dest = wave-uniform base + lane*16.
DEVI void gload16(const void* g, void* l) {
  __builtin_amdgcn_global_load_lds(
      (const __attribute__((address_space(1))) void*)g,
      (__attribute__((address_space(3))) void*)l, 16, 0, 0);
}

// ---------------------------------------------------------------------------
// Wcat build: per pair (w1,w2) make [2048,1024] bf16 where tile-row t7 of each
// 128-row block maps gate g=(t7>>4)&1, col (t7>>5)*16+(t7&15).  This puts G1
// and G2 for the same output col in the SAME thread (adjacent nf frags).
struct P6 { const float* p[6]; };

__global__ void cvt_wpair(P6 in, u16* __restrict__ out) {
  const int pair = blockIdx.y;
  const float* w1 = in.p[2 * pair];
  const float* w2 = in.p[2 * pair + 1];
  u16* dst = out + (size_t)pair * 2097152;
  const int i = blockIdx.x * 256 + threadIdx.x;   // grid.x = 1024 -> 262144
  const int v = i >> 7;                           // Wcat row 0..2047
  const int k0 = (i & 127) << 3;
  const int t7 = v & 127;
  const int g = (t7 >> 4) & 1;
  const int c = (v >> 7) * 64 + ((t7 >> 5) << 4) + (t7 & 15);
  const float* src = (g ? w2 : w1) + (size_t)c * 1024 + k0;
  const f32x4 a = *(const f32x4*)src;
  const f32x4 b = *(const f32x4*)(src + 4);
  u16x8 wv;
#pragma unroll
  for (int j = 0; j < 4; ++j) { wv[j] = f2b(a[j]); wv[4 + j] = f2b(b[j]); }
  *(u16x8*)(dst + (size_t)v * 1024 + k0) = wv;
}

// Generic f32 -> bf16 convert, 8 elems/thread (activations: grid 4096; wo: 512)
__global__ void cvt_x(const float* __restrict__ src, u16* __restrict__ dst) {
  const int i = blockIdx.x * 256 + threadIdx.x;
  const f32x4 a = ((const f32x4*)src)[i * 2];
  const f32x4 b = ((const f32x4*)src)[i * 2 + 1];
  u16x8 w;
#pragma unroll
  for (int j = 0; j < 4; ++j) { w[j] = f2b(a[j]); w[4 + j] = f2b(b[j]); }
  ((u16x8*)dst)[i] = w;
}

// ---------------------------------------------------------------------------
// 256x128 GEMM, BK=64, 512 thr (8 waves, 4x2 of 64x64), dbuf global_load_lds,
// 96 KB dynamic LDS.  XCD-swizzled so same-m blocks colocate (A L2-reuse).
// MODE 0: dual-gate swiglu -> Q/K [B,H,S,64] (scale folded)
// MODE 1: dual-gate swiglu -> V^T [B,H,64,S]
// MODE 2: plain C = A*W^T + b1 -> f32 [8192,1024]
template<int MODE>
__global__ __launch_bounds__(512, 2) void gemm256(
    const u16* __restrict__ Ap, const u16* __restrict__ Wp,
    const float* __restrict__ b1, const float* __restrict__ b2,
    void* __restrict__ outp, float scale)
{
  extern __shared__ char smem[];               // 2 x (As 32K | Ws 16K)
  const int t = threadIdx.x;
  const int lane = t & 63, wid = t >> 6;
  const int lg = lane >> 4, lc = lane & 15;
  const int wr = (wid >> 1) * 64;              // 0,64,128,192
  const int wc = (wid & 1) * 64;
  constexpr int NXB = (MODE == 2) ? 8 : 16;
  const int flat = blockIdx.y * NXB + blockIdx.x;
  const int w8 = flat >> 3, xcd = flat & 7;
  const int m0 = (xcd * 4 + w8 / NXB) * 256;   // same-m blocks share XCD
  const int bx = w8 % NXB;
  const int K = 1024;
  const int srow = lane >> 3, scolb = (lane & 7) << 4;

  const f32x4 fz = {0.f, 0.f, 0.f, 0.f};
  f32x4 acc[4][4];
#pragma unroll
  for (int i = 0; i < 4; ++i)
#pragma unroll
    for (int j = 0; j < 4; ++j) acc[i][j] = fz;

  auto STAGE = [&](int buf, int kt) {
    const int k0 = kt << 6;
    char* As = smem + buf * 49152;
    char* Ws = As + 32768;
#pragma unroll
    for (int p = 0; p < 4; ++p) {              // A: 256 rows
      const int rb = wid * 32 + p * 8;
      const int row = rb + srow;
      const int ce = (scolb ^ ((row & 7) << 4)) >> 1;
      gload16(Ap + (size_t)(m0 + row) * K + k0 + ce, As + rb * 128);
    }
#pragma unroll
    for (int p = 0; p < 2; ++p) {              // W: 128 rows
      const int rb = wid * 16 + p * 8;
      const int row = rb + srow;
      const int ce = (scolb ^ ((row & 7) << 4)) >> 1;
      gload16(Wp + (size_t)(bx * 128 + row) * K + k0 + ce, Ws + rb * 128);
    }
  };

  STAGE(0, 0);
  __syncthreads();
  for (int kt = 0; kt < 16; ++kt) {
    const int cur = kt & 1;
    if (kt < 15) STAGE(cur ^ 1, kt + 1);
    const char* As = smem + cur * 49152;
    const char* Ws = As + 32768;
#pragma unroll
    for (int kh = 0; kh < 2; ++kh) {
      bf16x8 af[4], bfr[4];
#pragma unroll
      for (int mf = 0; mf < 4; ++mf) {
        const int r = wr + mf * 16 + lc;
        af[mf] = *(const bf16x8*)(As + r * 128 + ((kh * 64 + (lg << 4)) ^ ((r & 7) << 4)));
      }
#pragma unroll
      for (int nf = 0; nf < 4; ++nf) {
        const int v = wc + nf * 16 + lc;
        bfr[nf] = *(const bf16x8*)(Ws + v * 128 + ((kh * 64 + (lg << 4)) ^ ((v & 7) << 4)));
      }
#pragma unroll
      for (int mf = 0; mf < 4; ++mf)
#pragma unroll
        for (int nf = 0; nf < 4; ++nf)
          acc[mf][nf] = mfma16(af[mf], bfr[nf], acc[mf][nf]);
    }
    __syncthreads();
  }
  // ---- epilogue ----
  if constexpr (MODE == 2) {
    float* Co = (float*)outp;
#pragma unroll
    for (int mf = 0; mf < 4; ++mf)
#pragma unroll
      for (int nf = 0; nf < 4; ++nf) {
        const int r0 = m0 + wr + mf * 16 + (lg << 2);
        const int C = bx * 128 + wc + nf * 16 + lc;
        const float bv = b1[C];
#pragma unroll
        for (int j = 0; j < 4; ++j)
          Co[(size_t)(r0 + j) * 1024 + C] = acc[mf][nf][j] + bv;
      }
  } else {
    u16* Co = (u16*)outp;
#pragma unroll
    for (int mf = 0; mf < 4; ++mf) {
      const int r0 = m0 + wr + mf * 16 + (lg << 2);
#pragma unroll
      for (int p = 0; p < 2; ++p) {            // acc pairs (2p, 2p+1) = (G1,G2)
        const int C = bx * 64 + (wid & 1) * 32 + p * 16 + lc;
        const float b1v = b1[C], b2v = b2[C];
        const int h = C >> 6, d = C & 63;
        if constexpr (MODE == 0) {
#pragma unroll
          for (int j = 0; j < 4; ++j) {
            const int r = r0 + j;
            const float x = acc[mf][2 * p][j] + b1v;
            const float y = acc[mf][2 * p + 1][j] + b2v;
            const float vv = (x / (1.f + __expf(-x))) * y * scale;
            const int bb = r >> 11, s = r & 2047;
            Co[((size_t)(bb * 16 + h) * 2048 + s) * 64 + d] = f2b(vv);
          }
        } else {
          u16x4 wv;
#pragma unroll
          for (int j = 0; j < 4; ++j) {
            const float x = acc[mf][2 * p][j] + b1v;
            const float y = acc[mf][2 * p + 1][j] + b2v;
            wv[j] = f2b((x / (1.f + __expf(-x))) * y);
          }
          const int bb = r0 >> 11, s0 = r0 & 2047;   // r0 % 4 == 0
          *(u16x4*)(Co + ((size_t)(bb * 16 + h) * 64 + d) * 2048 + s0) = wv;
        }
      }
    }
  }
}

// ---------------------------------------------------------------------------
// Causal flash attention.  64-q chunks, pair-balanced, XCD-swizzled,
// 4 blocks/CU.  Q pre-scaled by 0.125*log2e (exp2 domain).
// Row-sum via ones-MFMA (lacc); defer-max with THR (butterfly only on growth).
__global__ __launch_bounds__(256, 4) void attn_fwd(
    const u16* __restrict__ Q, const u16* __restrict__ Kk,
    const u16* __restrict__ Vt, u16* __restrict__ O)
{
  __shared__ char smem[40960];           // 2 x (K 8K | V 8K) + Pw 8K
  char* Pw = smem + 32768 + (threadIdx.x >> 6) * 2048;  // per-wave [16 q][128B]
  const int t = threadIdx.x;
  const int lane = t & 63, wid = t >> 6;
  const int lg = lane >> 4, lc = lane & 15;
  const int flat = blockIdx.y * 16 + blockIdx.x;
  const int fl2 = (flat & 7) * 128 + (flat >> 3);   // same-bh -> same XCD
  const int qi = fl2 & 15;
  const int bh = fl2 >> 4;
  const int b = bh >> 4, h = bh & 15;
  const f32x4 fz = {0.f, 0.f, 0.f, 0.f};
  const float THR = 11.5f;               // exp2-domain defer threshold (~e^8)

  bf16x8 onesb;
#pragma unroll
  for (int j = 0; j < 8; ++j) onesb[j] = (bf16)1.0f;

  auto STAGE = [&](int buf, int kt) {
    const int kbase = kt << 6;
    char* Kb = smem + buf * 16384;
    char* Vb = Kb + 8192;
#pragma unroll
    for (int p = 0; p < 4; ++p) {
      const int idx = wid * 4 + p;       // 0..15 (8 K-chunks, 8 V-chunks)
      const int rb = (idx & 7) * 8;
      const int row = rb + (lane >> 3);
      const int ce = (((lane & 7) << 4) ^ ((row & 7) << 4)) >> 1;
      if (idx < 8)
        gload16(Kk + ((size_t)bh * 2048 + kbase + row) * 64 + ce, Kb + rb * 128);
      else
        gload16(Vt + ((size_t)bh * 64 + row) * 2048 + kbase + ce, Vb + rb * 128);
    }
  };

  for (int pass = 0; pass < 2; ++pass) {
    const int qc = pass ? (31 - qi) : qi;
    const int q0 = qc * 64;
    const int qw = q0 + wid * 16;        // wave's first q row

    bf16x8 qf[2];                        // Q A-frags in regs for all tiles
#pragma unroll
    for (int kh = 0; kh < 2; ++kh) {
      const int r = qw + lc;
      qf[kh] = *(const bf16x8*)(Q + ((size_t)bh * 2048 + r) * 64 + kh * 32 + lg * 8);
    }

    f32x4 o[4], lacc = fz;
    float mrow[4];
#pragma unroll
    for (int dn = 0; dn < 4; ++dn) o[dn] = fz;
#pragma unroll
    for (int j = 0; j < 4; ++j) mrow[j] = -1e30f;

    const int nt = qc + 1;
    STAGE(0, 0);
    __syncthreads();
    for (int kt = 0; kt < nt; ++kt) {
      const int cur = kt & 1;
      if (kt + 1 < nt) STAGE(cur ^ 1, kt + 1);   // prefetch next tile
      const int kbase = kt << 6;
      const char* Ks = smem + cur * 16384;
      const char* Vs = Ks + 8192;
      // --- QK^T ---
      f32x4 sf[4];
#pragma unroll
      for (int nf = 0; nf < 4; ++nf) sf[nf] = fz;
      __builtin_amdgcn_s_setprio(1);
#pragma unroll
      for (int kh = 0; kh < 2; ++kh) {
        bf16x8 kb[4];
#pragma unroll
        for (int nf = 0; nf < 4; ++nf) {
          const int r = nf * 16 + lc;
          kb[nf] = *(const bf16x8*)(Ks + r * 128 + ((kh * 64 + (lg << 4)) ^ ((r & 7) << 4)));
        }
#pragma unroll
        for (int nf = 0; nf < 4; ++nf)
          sf[nf] = mfma16(qf[kh], kb[nf], sf[nf]);
      }
      __builtin_amdgcn_s_setprio(0);
      // --- causal mask (diagonal-overlap tiles only) ---
      if (kbase + 63 > qw) {
#pragma unroll
        for (int nf = 0; nf < 4; ++nf)
#pragma unroll
          for (int j = 0; j < 4; ++j) {
            const int qr = qw + (lg << 2) + j;
            const int kc = kbase + nf * 16 + lc;
            if (kc > qr) sf[nf][j] = -1e30f;
          }
      }
      // --- defer-max online softmax: cheap check, rare full path ---
      {
        float pm[4];
#pragma unroll
        for (int j = 0; j < 4; ++j)
          pm[j] = fmaxf(fmaxf(sf[0][j], sf[1][j]), fmaxf(sf[2][j], sf[3][j]));
        bool ok = true;
#pragma unroll
        for (int j = 0; j < 4; ++j) ok &= (pm[j] <= mrow[j] + THR);
        if (!__all(ok)) {                // max grew: butterfly + rescale
#pragma unroll
          for (int dd = 1; dd <= 8; dd <<= 1)
#pragma unroll
            for (int j = 0; j < 4; ++j)
              pm[j] = fmaxf(pm[j], __shfl_xor(pm[j], dd, 64));
          float scj[4];
#pragma unroll
          for (int j = 0; j < 4; ++j) {
            const float mn = fmaxf(mrow[j], pm[j]);
            scj[j] = exp2f(mrow[j] - mn);
            mrow[j] = mn;
          }
#pragma unroll
          for (int dn = 0; dn < 4; ++dn)
#pragma unroll
            for (int j = 0; j < 4; ++j)
              o[dn][j] *= scj[j];
#pragma unroll
          for (int j = 0; j < 4; ++j) lacc[j] *= scj[j];
        }
        // P = exp2(sf - mrow), bounded by 2^THR; write to per-wave LDS
#pragma unroll
        for (int nf = 0; nf < 4; ++nf)
#pragma unroll
          for (int j = 0; j < 4; ++j) {
            const float p = exp2f(sf[nf][j] - mrow[j]);
            const int pr = (lg << 2) + j;
            const int pcb = (nf * 16 + lc) << 1;
            *(u16*)(Pw + pr * 128 + (pcb ^ ((pr & 7) << 4))) = f2b(p);
          }
      }
      // --- PV + ones-MFMA rowsum ---
      __builtin_amdgcn_s_setprio(1);
#pragma unroll
      for (int kh = 0; kh < 2; ++kh) {
        const int pr = lc;
        const bf16x8 pa = *(const bf16x8*)(Pw + pr * 128 + ((kh * 64 + (lg << 4)) ^ ((pr & 7) << 4)));
        lacc = mfma16(pa, onesb, lacc);  // row-sum of P (all cols identical)
#pragma unroll
        for (int dn = 0; dn < 4; ++dn) {
          const int vr = dn * 16 + lc;
          const bf16x8 vb = *(const bf16x8*)(Vs + vr * 128 + ((kh * 64 + (lg << 4)) ^ ((vr & 7) << 4)));
          o[dn] = mfma16(pa, vb, o[dn]);
        }
      }
      __builtin_amdgcn_s_setprio(0);
      __syncthreads();                   // next buffer staged; cur reusable
    }
    // epilogue: O[b, s, h*64+d] = o / l
#pragma unroll
    for (int j = 0; j < 4; ++j) {
      const float inv = __builtin_amdgcn_rcpf(lacc[j]);
      const int s = qw + (lg << 2) + j;
#pragma unroll
      for (int dn = 0; dn < 4; ++dn) {
        const int d = dn * 16 + lc;
        O[((size_t)(b * 2048 + s) * 16 + h) * 64 + d] = f2b(o[dn][j] * inv);
      }
    }
  }
}

// ---------------------------------------------------------------------------
extern "C" void kernel_launch(void* const* d_in, const int* in_sizes, int n_in,
                              void* d_out, int out_size, void* d_ws, size_t ws_size,
                              hipStream_t stream)
{
  (void)in_sizes; (void)n_in; (void)out_size; (void)ws_size;
  const float* xq  = (const float*)d_in[0];
  const float* xk  = (const float*)d_in[1];
  const float* xv  = (const float*)d_in[2];
  // d_in[3] = causal mask -- hardcoded in attn_fwd
  const float* wq1 = (const float*)d_in[4];
  const float* bq1 = (const float*)d_in[5];
  const float* wq2 = (const float*)d_in[6];
  const float* bq2 = (const float*)d_in[7];
  const float* wk1 = (const float*)d_in[8];
  const float* bk1 = (const float*)d_in[9];
  const float* wk2 = (const float*)d_in[10];
  const float* bk2 = (const float*)d_in[11];
  const float* wv1 = (const float*)d_in[12];
  const float* bv1 = (const float*)d_in[13];
  const float* wv2 = (const float*)d_in[14];
  const float* bv2 = (const float*)d_in[15];
  const float* wo  = (const float*)d_in[16];
  const float* bo  = (const float*)d_in[17];

  // Workspace: WB 14MB | XB/AO 16MB | (free) | QB | KB | VT  (94 MB, unchanged)
  char* ws = (char*)d_ws;
  u16* WB = (u16*)ws;                    // 3x Wcat (2M elems each) + wo (1M)
  u16* XB = (u16*)(ws + 14680064);       // converted activation; AO after V-proj
  u16* QB = (u16*)(ws + 48234496);       // [BH,S,64], exp2-prescaled
  u16* KB = (u16*)(ws + 65011712);       // [BH,S,64]
  u16* VT = (u16*)(ws + 81788928);       // [BH,64,S]
  u16* AO = XB;                          // attn out aliases dead XB
  u16* WCQ = WB;
  u16* WCK = WB + 2097152;
  u16* WCV = WB + 4194304;
  u16* WO  = WB + 6291456;

  P6 p6 = {{wq1, wq2, wk1, wk2, wv1, wv2}};
  cvt_wpair<<<dim3(1024, 3), 256, 0, stream>>>(p6, WB);
  cvt_x<<<512, 256, 0, stream>>>(wo, WO);

  const float QSCALE = 0.125f * 1.44269504088896f;  // 1/sqrt(dk) * log2(e)
  const dim3 gs(16, 32);                 // swiglu grid (64 cols x 256 rows)
  // Q projection
  cvt_x<<<4096, 256, 0, stream>>>(xq, XB);
  gemm256<0><<<gs, 512, 98304, stream>>>(XB, WCQ, bq1, bq2, QB, QSCALE);
  // K projection
  cvt_x<<<4096, 256, 0, stream>>>(xk, XB);
  gemm256<0><<<gs, 512, 98304, stream>>>(XB, WCK, bk1, bk2, KB, 1.0f);
  // V projection (transposed output)
  cvt_x<<<4096, 256, 0, stream>>>(xv, XB);
  gemm256<1><<<gs, 512, 98304, stream>>>(XB, WCV, bv1, bv2, VT, 1.0f);
  // attention
  attn_fwd<<<dim3(16, 64), 256, 0, stream>>>(QB, KB, VT, AO);
  // output projection
  gemm256<2><<<dim3(8, 32), 512, 98304, stream>>>(AO, WO, bo, nullptr, d_out, 1.0f);
}

// Round 6
// 244.641 us; speedup vs baseline: 2.1788x; 1.0719x over previous
//
#include <hip/hip_runtime.h>

// B=4, S=2048, D_MODEL=1024, H=16, DK=64.  M = B*S = 8192.
// cvt weights (Wcat) -> cvt acts -> fused dual-gate swiglu GEMMs (Q+K fused
// dispatch, V) -> causal flash attention (swapped QK^T, in-register softmax,
// permlane P-transpose) -> output GEMM.

typedef __bf16 bf16;
typedef bf16 bf16x8 __attribute__((ext_vector_type(8)));
typedef float f32x4 __attribute__((ext_vector_type(4)));
typedef unsigned short u16;
typedef unsigned int u32;
typedef u16 u16x8 __attribute__((ext_vector_type(8)));
typedef u16 u16x4 __attribute__((ext_vector_type(4)));

#define DEVI static __device__ __forceinline__

DEVI u16 f2b(float f) {                    // f32 -> bf16 bits, RNE
  union { float f; u32 u; } v; v.f = f;
  u32 r = v.u + 0x7FFFu + ((v.u >> 16) & 1u);
  return (u16)(r >> 16);
}
DEVI f32x4 mfma16(bf16x8 a, bf16x8 b, f32x4 c) {
  return __builtin_amdgcn_mfma_f32_16x16x32_bf16(a, b, c, 0, 0, 0);
}
DEVI void gload16(const void* g, void* l) {
  __builtin_amdgcn_global_load_lds(
      (const __attribute__((address_space(1))) void*)g,
      (__attribute__((address_space(3))) void*)l, 16, 0, 0);
}
DEVI u32 cvtpk(float lo, float hi) {       // bf16 pair, RNE
  u32 r;
  asm("v_cvt_pk_bf16_f32 %0, %1, %2" : "=v"(r) : "v"(lo), "v"(hi));
  return r;
}
DEVI void pswap(u32& a, u32& b) {          // a' = [a.lo|b.lo], b' = [a.hi|b.hi]
  asm("v_permlane32_swap_b32 %0, %1" : "+v"(a), "+v"(b));
}

// ---------------------------------------------------------------------------
// Wcat build: per pair (w1,w2) -> [2048,1024] bf16; tile-row t7 of each
// 128-row block maps gate g=(t7>>4)&1, col (t7>>5)*16+(t7&15).  Puts G1/G2 of
// the same output col in the same thread (adjacent nf frags).
struct P6 { const float* p[6]; };

__global__ void cvt_wpair(P6 in, u16* __restrict__ out) {
  const int pair = blockIdx.y;
  const float* w1 = in.p[2 * pair];
  const float* w2 = in.p[2 * pair + 1];
  u16* dst = out + (size_t)pair * 2097152;
  const int i = blockIdx.x * 256 + threadIdx.x;   // grid.x = 1024
  const int v = i >> 7;                           // Wcat row 0..2047
  const int k0 = (i & 127) << 3;
  const int t7 = v & 127;
  const int g = (t7 >> 4) & 1;
  const int c = (v >> 7) * 64 + ((t7 >> 5) << 4) + (t7 & 15);
  const float* src = (g ? w2 : w1) + (size_t)c * 1024 + k0;
  const f32x4 a = *(const f32x4*)src;
  const f32x4 b = *(const f32x4*)(src + 4);
  u16x8 wv;
#pragma unroll
  for (int j = 0; j < 4; ++j) { wv[j] = f2b(a[j]); wv[4 + j] = f2b(b[j]); }
  *(u16x8*)(dst + (size_t)v * 1024 + k0) = wv;
}

// f32 -> bf16, 8 elems/thread; grid.y selects (s0,d0) or (s1,d1).
__global__ void cvt_x(const float* __restrict__ s0, u16* __restrict__ d0,
                      const float* __restrict__ s1, u16* __restrict__ d1) {
  const float* src = blockIdx.y ? s1 : s0;
  u16* dst = blockIdx.y ? d1 : d0;
  const int i = blockIdx.x * 256 + threadIdx.x;
  const f32x4 a = ((const f32x4*)src)[i * 2];
  const f32x4 b = ((const f32x4*)src)[i * 2 + 1];
  u16x8 w;
#pragma unroll
  for (int j = 0; j < 4; ++j) { w[j] = f2b(a[j]); w[4 + j] = f2b(b[j]); }
  ((u16x8*)dst)[i] = w;
}

// ---------------------------------------------------------------------------
// 256x128 GEMM, BK=64, 512 thr (8 waves), dbuf global_load_lds, 96 KB LDS.
// MODE 0: dual-gate swiglu -> Q/K [B,H,S,64]; MODE 1: swiglu -> V^T [B,H,64,S];
// MODE 2: plain + bias -> f32.  DUAL: blocks >= 512 use the second arg set.
struct GArgs {
  const u16* A; const u16* W;
  const float* b1; const float* b2;
  void* out; float scale;
};

template<int MODE, bool DUAL>
__global__ __launch_bounds__(512, 2) void gemm256(GArgs g0, GArgs g1)
{
  extern __shared__ char smem[];               // 2 x (As 32K | Ws 16K)
  const int fl = blockIdx.x;
  const GArgs g = (DUAL && fl >= 512) ? g1 : g0;
  const int local = DUAL ? (fl & 511) : fl;
  const int t = threadIdx.x;
  const int lane = t & 63, wid = t >> 6;
  const int lg = lane >> 4, lc = lane & 15;
  const int wr = (wid >> 1) * 64;
  const int wc = (wid & 1) * 64;
  constexpr int NXB = (MODE == 2) ? 8 : 16;
  const int xcd = local & 7, w8 = local >> 3;
  const int m0 = (xcd * 4 + w8 / NXB) * 256;   // same-m blocks share XCD
  const int bx = w8 % NXB;
  const int K = 1024;
  const int srow = lane >> 3, scolb = (lane & 7) << 4;

  const f32x4 fz = {0.f, 0.f, 0.f, 0.f};
  f32x4 acc[4][4];
#pragma unroll
  for (int i = 0; i < 4; ++i)
#pragma unroll
    for (int j = 0; j < 4; ++j) acc[i][j] = fz;

  auto STAGE = [&](int buf, int kt) {
    const int k0 = kt << 6;
    char* As = smem + buf * 49152;
    char* Ws = As + 32768;
#pragma unroll
    for (int p = 0; p < 4; ++p) {              // A: 256 rows
      const int rb = wid * 32 + p * 8;
      const int row = rb + srow;
      const int ce = (scolb ^ ((row & 7) << 4)) >> 1;
      gload16(g.A + (size_t)(m0 + row) * K + k0 + ce, As + rb * 128);
    }
#pragma unroll
    for (int p = 0; p < 2; ++p) {              // W: 128 rows
      const int rb = wid * 16 + p * 8;
      const int row = rb + srow;
      const int ce = (scolb ^ ((row & 7) << 4)) >> 1;
      gload16(g.W + (size_t)(bx * 128 + row) * K + k0 + ce, Ws + rb * 128);
    }
  };

  STAGE(0, 0);
  __syncthreads();
  for (int kt = 0; kt < 16; ++kt) {
    const int cur = kt & 1;
    if (kt < 15) STAGE(cur ^ 1, kt + 1);
    const char* As = smem + cur * 49152;
    const char* Ws = As + 32768;
#pragma unroll
    for (int kh = 0; kh < 2; ++kh) {
      bf16x8 af[4], bfr[4];
#pragma unroll
      for (int mf = 0; mf < 4; ++mf) {
        const int r = wr + mf * 16 + lc;
        af[mf] = *(const bf16x8*)(As + r * 128 + ((kh * 64 + (lg << 4)) ^ ((r & 7) << 4)));
      }
#pragma unroll
      for (int nf = 0; nf < 4; ++nf) {
        const int v = wc + nf * 16 + lc;
        bfr[nf] = *(const bf16x8*)(Ws + v * 128 + ((kh * 64 + (lg << 4)) ^ ((v & 7) << 4)));
      }
#pragma unroll
      for (int mf = 0; mf < 4; ++mf)
#pragma unroll
        for (int nf = 0; nf < 4; ++nf)
          acc[mf][nf] = mfma16(af[mf], bfr[nf], acc[mf][nf]);
    }
    __syncthreads();
  }
  // ---- epilogue ----
  if constexpr (MODE == 2) {
    float* Co = (float*)g.out;
#pragma unroll
    for (int mf = 0; mf < 4; ++mf)
#pragma unroll
      for (int nf = 0; nf < 4; ++nf) {
        const int r0 = m0 + wr + mf * 16 + (lg << 2);
        const int C = bx * 128 + wc + nf * 16 + lc;
        const float bv = g.b1[C];
#pragma unroll
        for (int j = 0; j < 4; ++j)
          Co[(size_t)(r0 + j) * 1024 + C] = acc[mf][nf][j] + bv;
      }
  } else {
    u16* Co = (u16*)g.out;
#pragma unroll
    for (int mf = 0; mf < 4; ++mf) {
      const int r0 = m0 + wr + mf * 16 + (lg << 2);
#pragma unroll
      for (int p = 0; p < 2; ++p) {            // acc pairs (2p, 2p+1) = (G1,G2)
        const int C = bx * 64 + (wid & 1) * 32 + p * 16 + lc;
        const float b1v = g.b1[C], b2v = g.b2[C];
        const int h = C >> 6, d = C & 63;
        if constexpr (MODE == 0) {
#pragma unroll
          for (int j = 0; j < 4; ++j) {
            const int r = r0 + j;
            const float x = acc[mf][2 * p][j] + b1v;
            const float y = acc[mf][2 * p + 1][j] + b2v;
            const float vv = (x / (1.f + __expf(-x))) * y * g.scale;
            const int bb = r >> 11, s = r & 2047;
            Co[((size_t)(bb * 16 + h) * 2048 + s) * 64 + d] = f2b(vv);
          }
        } else {
          u16x4 wv;
#pragma unroll
          for (int j = 0; j < 4; ++j) {
            const float x = acc[mf][2 * p][j] + b1v;
            const float y = acc[mf][2 * p + 1][j] + b2v;
            wv[j] = f2b((x / (1.f + __expf(-x))) * y);
          }
          const int bb = r0 >> 11, s0 = r0 & 2047;   // r0 % 4 == 0
          *(u16x4*)(Co + ((size_t)(bb * 16 + h) * 64 + d) * 2048 + s0) = wv;
        }
      }
    }
  }
}

// ---------------------------------------------------------------------------
// Causal flash attention.  Swapped QK^T (S^T in regs: row=k, col=q=lane&15),
// fully in-register softmax (per-lane scalar m/l, xor16/32 reduce),
// cvt_pk + permlane32_swap P-transpose, PV as O^T = V^T * P^T.
// 64-q chunks, pair-balanced {qi, 31-qi}, XCD-swizzled, 4 blocks/CU.
// Q pre-scaled by 0.125*log2e (exp2 domain).
__global__ __launch_bounds__(256, 4) void attn_fwd(
    const u16* __restrict__ Q, const u16* __restrict__ Kk,
    const u16* __restrict__ Vt, u16* __restrict__ O)
{
  __shared__ char smem[32768];           // 2 x (K 8K | V 8K)
  const int t = threadIdx.x;
  const int lane = t & 63, wid = t >> 6;
  const int lg = lane >> 4, lc = lane & 15;
  const int flat = blockIdx.y * 16 + blockIdx.x;
  const int fl2 = (flat & 7) * 128 + (flat >> 3);   // same-bh -> same XCD
  const int qi = fl2 & 15;
  const int bh = fl2 >> 4;
  const int b = bh >> 4, h = bh & 15;
  const f32x4 fz = {0.f, 0.f, 0.f, 0.f};
  const float THR = 11.5f;               // defer threshold (exp2 domain)
  const bool ev = ((lg & 1) == 0);

  auto STAGE = [&](int buf, int kt) {
    const int kbase = kt << 6;
    char* Kb = smem + buf * 16384;
    char* Vb = Kb + 8192;
#pragma unroll
    for (int p = 0; p < 4; ++p) {
      const int idx = wid * 4 + p;       // 0..15 (8 K-chunks, 8 V-chunks)
      const int rb = (idx & 7) * 8;
      const int row = rb + (lane >> 3);
      const int ce = (((lane & 7) << 4) ^ ((row & 7) << 4)) >> 1;
      if (idx < 8)
        gload16(Kk + ((size_t)bh * 2048 + kbase + row) * 64 + ce, Kb + rb * 128);
      else
        gload16(Vt + ((size_t)bh * 64 + row) * 2048 + kbase + ce, Vb + rb * 128);
    }
  };

  for (int pass = 0; pass < 2; ++pass) {
    const int qc = pass ? (31 - qi) : qi;
    const int qw = qc * 64 + wid * 16;   // wave's first q row

    bf16x8 qf[2];                        // Q as B-operand: col=q=lc, k=lg*8+e
#pragma unroll
    for (int kh = 0; kh < 2; ++kh)
      qf[kh] = *(const bf16x8*)(Q + ((size_t)bh * 2048 + qw + lc) * 64 + kh * 32 + lg * 8);

    f32x4 o[4];                          // O^T frags: row=d, col=q=lc
#pragma unroll
    for (int dn = 0; dn < 4; ++dn) o[dn] = fz;
    float mrow = -1e30f, lsum = 0.f;     // per-lane (q = lc)

    const int nt = qc + 1;
    STAGE(0, 0);
    __syncthreads();
    for (int kt = 0; kt < nt; ++kt) {
      const int cur = kt & 1;
      if (kt + 1 < nt) STAGE(cur ^ 1, kt + 1);   // prefetch next tile
      const char* Ks = smem + cur * 16384;
      const char* Vs = Ks + 8192;
      // --- QK^T (swapped): sfT[nf] row k = nf*16+lg*4+j, col q = lc ---
      f32x4 sfT[4];
#pragma unroll
      for (int nf = 0; nf < 4; ++nf) sfT[nf] = fz;
      __builtin_amdgcn_s_setprio(1);
#pragma unroll
      for (int kh = 0; kh < 2; ++kh) {
        bf16x8 kb[4];
#pragma unroll
        for (int nf = 0; nf < 4; ++nf) {
          const int r = nf * 16 + lc;
          kb[nf] = *(const bf16x8*)(Ks + r * 128 + ((kh * 64 + (lg << 4)) ^ ((r & 7) << 4)));
        }
#pragma unroll
        for (int nf = 0; nf < 4; ++nf)
          sfT[nf] = mfma16(kb[nf], qf[kh], sfT[nf]);
      }
      __builtin_amdgcn_s_setprio(0);
      // --- causal mask (only the last = diagonal tile needs it) ---
      if (kt == nt - 1) {
        const int kb0 = kt * 64 + (lg << 2);
        const int qq = qw + lc;
#pragma unroll
        for (int nf = 0; nf < 4; ++nf)
#pragma unroll
          for (int j = 0; j < 4; ++j)
            if (kb0 + nf * 16 + j > qq) sfT[nf][j] = -1e30f;
      }
      // --- per-lane max over 16 regs, then 2-step lane-group reduce ---
      float pm = sfT[0][0];
#pragma unroll
      for (int nf = 0; nf < 4; ++nf)
#pragma unroll
        for (int j = 0; j < 4; ++j) pm = fmaxf(pm, sfT[nf][j]);
      pm = fmaxf(pm, __shfl_xor(pm, 16));
      pm = fmaxf(pm, __shfl_xor(pm, 32));
      if (!__all(pm <= mrow + THR)) {    // defer-max: rescale only on growth
        const float mn = fmaxf(mrow, pm);
        const float sc = exp2f(mrow - mn);
        mrow = mn;
        lsum *= sc;
#pragma unroll
        for (int dn = 0; dn < 4; ++dn)
#pragma unroll
          for (int j = 0; j < 4; ++j) o[dn][j] *= sc;
      }
      float p[4][4];
#pragma unroll
      for (int nf = 0; nf < 4; ++nf)
#pragma unroll
        for (int j = 0; j < 4; ++j) {
          p[nf][j] = exp2f(sfT[nf][j] - mrow);
          lsum += p[nf][j];
        }
      // --- P^T regs -> PV B-frag: cvt_pk pairs + permlane32_swap + xor16 ---
      u32 pw[2][4];
#pragma unroll
      for (int kh = 0; kh < 2; ++kh) {
        u32 A0 = cvtpk(p[2 * kh][0], p[2 * kh][1]);
        u32 A1 = cvtpk(p[2 * kh][2], p[2 * kh][3]);
        u32 B0 = cvtpk(p[2 * kh + 1][0], p[2 * kh + 1][1]);
        u32 B1 = cvtpk(p[2 * kh + 1][2], p[2 * kh + 1][3]);
        pswap(A0, B0);                   // A0=[A.lo|B.lo], B0=[A.hi|B.hi]
        pswap(A1, B1);
        const u32 P0s = __shfl_xor(A0, 16);
        const u32 Q0s = __shfl_xor(B0, 16);
        const u32 P1s = __shfl_xor(A1, 16);
        const u32 Q1s = __shfl_xor(B1, 16);
        pw[kh][0] = ev ? A0 : Q0s;       // word w holds k = 32kh+8lg+{2w,2w+1}
        pw[kh][1] = ev ? A1 : Q1s;
        pw[kh][2] = ev ? P0s : B0;
        pw[kh][3] = ev ? P1s : B1;
      }
      // --- PV: O^T[d][q] += V^T[d][k] * P^T[k][q] ---
      __builtin_amdgcn_s_setprio(1);
#pragma unroll
      for (int kh = 0; kh < 2; ++kh) {
        union { u32 u[4]; bf16x8 v; } pc;
#pragma unroll
        for (int w = 0; w < 4; ++w) pc.u[w] = pw[kh][w];
        const bf16x8 pa = pc.v;
#pragma unroll
        for (int dn = 0; dn < 4; ++dn) {
          const int vr = dn * 16 + lc;
          const bf16x8 vb = *(const bf16x8*)(Vs + vr * 128 + ((kh * 64 + (lg << 4)) ^ ((vr & 7) << 4)));
          o[dn] = mfma16(vb, pa, o[dn]);
        }
      }
      __builtin_amdgcn_s_setprio(0);
      __syncthreads();                   // next buffer staged; cur reusable
    }
    // --- epilogue: O[b, s=qw+lc, h, d=dn*16+lg*4+j] = o / lsum ---
    lsum += __shfl_xor(lsum, 16);
    lsum += __shfl_xor(lsum, 32);
    const float inv = __builtin_amdgcn_rcpf(lsum);
    const size_t ob = ((size_t)(b * 2048 + qw + lc) * 16 + h) * 64 + (lg << 2);
#pragma unroll
    for (int dn = 0; dn < 4; ++dn) {
      u16x4 wv;
#pragma unroll
      for (int j = 0; j < 4; ++j) wv[j] = f2b(o[dn][j] * inv);
      *(u16x4*)(O + ob + dn * 16) = wv;
    }
  }
}

// ---------------------------------------------------------------------------
extern "C" void kernel_launch(void* const* d_in, const int* in_sizes, int n_in,
                              void* d_out, int out_size, void* d_ws, size_t ws_size,
                              hipStream_t stream)
{
  (void)in_sizes; (void)n_in; (void)out_size; (void)ws_size;
  const float* xq  = (const float*)d_in[0];
  const float* xk  = (const float*)d_in[1];
  const float* xv  = (const float*)d_in[2];
  // d_in[3] = causal mask -- hardcoded in attn_fwd
  const float* wq1 = (const float*)d_in[4];
  const float* bq1 = (const float*)d_in[5];
  const float* wq2 = (const float*)d_in[6];
  const float* bq2 = (const float*)d_in[7];
  const float* wk1 = (const float*)d_in[8];
  const float* bk1 = (const float*)d_in[9];
  const float* wk2 = (const float*)d_in[10];
  const float* bk2 = (const float*)d_in[11];
  const float* wv1 = (const float*)d_in[12];
  const float* bv1 = (const float*)d_in[13];
  const float* wv2 = (const float*)d_in[14];
  const float* bv2 = (const float*)d_in[15];
  const float* wo  = (const float*)d_in[16];
  const float* bo  = (const float*)d_in[17];

  // Workspace (98.5 MB, same as prior rounds):
  // WB 14MB | XQ 16.7 (later XV) | XK 16.7 (later AO) | QB | KB | VT
  char* ws = (char*)d_ws;
  u16* WB = (u16*)ws;
  u16* XQ = (u16*)(ws + 14680064);
  u16* XK = (u16*)(ws + 31457280);
  u16* QB = (u16*)(ws + 48234496);
  u16* KB = (u16*)(ws + 65011712);
  u16* VT = (u16*)(ws + 81788928);
  u16* XV = XQ;                          // XQ dead after the Q+K swiglu
  u16* AO = XK;                          // XK dead after the Q+K swiglu
  u16* WCQ = WB;
  u16* WCK = WB + 2097152;
  u16* WCV = WB + 4194304;
  u16* WO  = WB + 6291456;

  P6 p6 = {{wq1, wq2, wk1, wk2, wv1, wv2}};
  cvt_wpair<<<dim3(1024, 3), 256, 0, stream>>>(p6, WB);
  cvt_x<<<dim3(512, 1), 256, 0, stream>>>(wo, WO, wo, WO);
  cvt_x<<<dim3(4096, 2), 256, 0, stream>>>(xq, XQ, xk, XK);

  const float QSCALE = 0.125f * 1.44269504088896f;  // 1/sqrt(dk) * log2(e)
  GArgs gq = {XQ, WCQ, bq1, bq2, QB, QSCALE};
  GArgs gk = {XK, WCK, bk1, bk2, KB, 1.0f};
  gemm256<0, true><<<1024, 512, 98304, stream>>>(gq, gk);

  cvt_x<<<dim3(4096, 1), 256, 0, stream>>>(xv, XV, xv, XV);
  GArgs gv = {XV, WCV, bv1, bv2, VT, 1.0f};
  gemm256<1, false><<<512, 512, 98304, stream>>>(gv, gv);

  attn_fwd<<<dim3(16, 64), 256, 0, stream>>>(QB, KB, VT, AO);

  GArgs go = {AO, WO, bo, nullptr, d_out, 1.0f};
  gemm256<2, false><<<256, 512, 98304, stream>>>(go, go);
}